// Round 5
// baseline (656.034 us; speedup 1.0000x reference)
//
#include <hip/hip_runtime.h>
#include <hip/hip_bf16.h>

#define NN 50000
#define NE 800000
#define HD 256
#define KIN 128
#define SCAN_B 49
#define DMAX 128

typedef __attribute__((ext_vector_type(8))) short bf16x8;
typedef __attribute__((ext_vector_type(8))) short short8v;
typedef __attribute__((ext_vector_type(4))) float f32x4;

static __device__ __forceinline__ short f2b(float f){
  union { __hip_bfloat16 h; short s; } u;
  u.h = __float2bfloat16(f);
  return u.s;
}
static __device__ __forceinline__ float b2f(short s){
  union { __hip_bfloat16 h; short s; } u;
  u.s = s;
  return __bfloat162float(u.h);
}
// softplus(x) - log(2), hw transcendentals
static __device__ __forceinline__ float sspf(float x){
  const float t = __expf(-fabsf(x));
  return fmaxf(x, 0.0f) + __logf(1.0f + t) - 0.69314718055994531f;
}
static __device__ __forceinline__ f32x4 leaky4(f32x4 x){
  f32x4 r;
#pragma unroll
  for (int k=0;k<4;++k) r[k] = x[k] > 0.f ? x[k] : 0.2f*x[k];
  return r;
}
static __device__ __forceinline__ f32x4 max4(f32x4 a, f32x4 b){
  f32x4 r;
#pragma unroll
  for (int k=0;k<4;++k) r[k] = fmaxf(a[k], b[k]);
  return r;
}
static __device__ __forceinline__ f32x4 exp4(f32x4 x){
  f32x4 r;
#pragma unroll
  for (int k=0;k<4;++k) r[k] = __expf(x[k]);
  return r;
}

// ---------- weight fp32 -> bf16 ----------
__global__ void k_convert(const float* __restrict__ wfc, const float* __restrict__ we1,
                          const float* __restrict__ we2,
                          short* __restrict__ wfcb, short* __restrict__ we1b,
                          short* __restrict__ we2b){
  const int i = blockIdx.x*256 + threadIdx.x;
  if (i < HD*KIN) wfcb[i] = f2b(wfc[i]);
  if (i < 32*KIN) we1b[i] = f2b(we1[i]);
  if (i < HD*32)  we2b[i] = f2b(we2[i]);
}

// ---------- feat = nfeat @ W_fc^T  (+ el, er) ----------
__global__ __launch_bounds__(256) void k_feat(
    const float* __restrict__ nfeat, const short* __restrict__ wfcb,
    const float* __restrict__ attn_l, const float* __restrict__ attn_r,
    short* __restrict__ featb, float* __restrict__ el, float* __restrict__ er)
{
  const int n0 = blockIdx.x * 64;
  const int tid = threadIdx.x;
  const int w = tid >> 6, l = tid & 63, l15 = l & 15, lq = l >> 4;

  f32x4 acc[4][4];
#pragma unroll
  for (int a=0;a<4;++a)
#pragma unroll
    for (int b=0;b<4;++b) acc[a][b] = (f32x4)0.0f;

#pragma unroll
  for (int ks=0; ks<4; ++ks){
    const int k0 = ks*32 + lq*8;
    bf16x8 af[4];
#pragma unroll
    for (int tr=0; tr<4; ++tr){
      int row = n0 + tr*16 + l15;
      if (row >= NN) row = NN-1;
      const float4 x0 = *reinterpret_cast<const float4*>(nfeat + (size_t)row*KIN + k0);
      const float4 x1 = *reinterpret_cast<const float4*>(nfeat + (size_t)row*KIN + k0 + 4);
      af[tr][0]=f2b(x0.x); af[tr][1]=f2b(x0.y); af[tr][2]=f2b(x0.z); af[tr][3]=f2b(x0.w);
      af[tr][4]=f2b(x1.x); af[tr][5]=f2b(x1.y); af[tr][6]=f2b(x1.z); af[tr][7]=f2b(x1.w);
    }
#pragma unroll
    for (int tc=0; tc<4; ++tc){
      const int c = w*64 + tc*16 + l15;
      const bf16x8 bfrag = *reinterpret_cast<const bf16x8*>(wfcb + c*KIN + k0);
#pragma unroll
      for (int tr=0; tr<4; ++tr)
        acc[tr][tc] = __builtin_amdgcn_mfma_f32_16x16x32_bf16(af[tr], bfrag, acc[tr][tc], 0,0,0);
    }
  }

  float alr[4], arr_[4];
#pragma unroll
  for (int tc=0;tc<4;++tc){
    const int c = w*64 + tc*16 + l15;
    alr[tc] = attn_l[c]; arr_[tc] = attn_r[c];
  }
  float pl[4][4][2], pr[4][4][2];
#pragma unroll
  for (int tr=0;tr<4;++tr)
#pragma unroll
    for (int j=0;j<4;++j){ pl[tr][j][0]=pl[tr][j][1]=0.f; pr[tr][j][0]=pr[tr][j][1]=0.f; }

#pragma unroll
  for (int tr=0;tr<4;++tr){
    const int rowb = tr*16 + lq*4;
#pragma unroll
    for (int tc=0;tc<4;++tc){
      const int c = w*64 + tc*16 + l15;
      const int h2 = tc>>1;
#pragma unroll
      for (int j=0;j<4;++j){
        const float v = acc[tr][tc][j];
        const int node = n0 + rowb + j;
        if (node < NN) featb[node*HD + c] = f2b(v);
        pl[tr][j][h2] += v*alr[tc];
        pr[tr][j][h2] += v*arr_[tc];
      }
    }
  }
#pragma unroll
  for (int m=1;m<16;m<<=1){
#pragma unroll
    for (int tr=0;tr<4;++tr)
#pragma unroll
      for (int j=0;j<4;++j){
        pl[tr][j][0] += __shfl_xor(pl[tr][j][0], m, 64);
        pl[tr][j][1] += __shfl_xor(pl[tr][j][1], m, 64);
        pr[tr][j][0] += __shfl_xor(pr[tr][j][0], m, 64);
        pr[tr][j][1] += __shfl_xor(pr[tr][j][1], m, 64);
      }
  }
#pragma unroll
  for (int tr=0;tr<4;++tr)
#pragma unroll
    for (int j=0;j<4;++j)
      if (l15 == tr*4+j){
        const int node = n0 + tr*16 + lq*4 + j;
        if (node < NN){
          el[node*8 + 2*w + 0] = pl[tr][j][0];
          el[node*8 + 2*w + 1] = pl[tr][j][1];
          er[node*8 + 2*w + 0] = pr[tr][j][0];
          er[node*8 + 2*w + 1] = pr[tr][j][1];
        }
      }
}

// ---------- CSR build ----------
__global__ void k_hist(const int* __restrict__ dst, int* __restrict__ deg){
  for (int i = blockIdx.x*blockDim.x + threadIdx.x; i < NE; i += gridDim.x*blockDim.x)
    atomicAdd(&deg[dst[i]], 1);
}

__global__ __launch_bounds__(1024) void k_scanA(const int* __restrict__ deg,
                                                int* __restrict__ bsum){
  __shared__ int ws[16];
  const int t = threadIdx.x;
  const int i = blockIdx.x*1024 + t;
  int v = (i < NN) ? deg[i] : 0;
#pragma unroll
  for (int m=1;m<64;m<<=1) v += __shfl_xor(v, m, 64);
  if ((t & 63) == 0) ws[t >> 6] = v;
  __syncthreads();
  if (t == 0){
    int s = 0;
#pragma unroll
    for (int k=0;k<16;++k) s += ws[k];
    bsum[blockIdx.x] = s;
  }
}
__global__ void k_scanB(const int* __restrict__ bsum, int* __restrict__ boff,
                        int* __restrict__ total){
  const int t = threadIdx.x;  // 64 threads
  const int v = (t < SCAN_B) ? bsum[t] : 0;
  int x = v;
#pragma unroll
  for (int off=1; off<64; off<<=1){
    const int y = __shfl_up(x, off, 64);
    if (t >= off) x += y;
  }
  if (t < SCAN_B) boff[t] = x - v;
  if (t == 63) *total = x;
}
__global__ __launch_bounds__(1024) void k_scanC(const int* __restrict__ deg,
                                                const int* __restrict__ boff,
                                                const int* __restrict__ total,
                                                int* __restrict__ rowptr,
                                                int* __restrict__ fillptr){
  __shared__ int ws[16];
  const int t = threadIdx.x, l = t & 63, wid = t >> 6;
  const int i = blockIdx.x*1024 + t;
  const int v = (i < NN) ? deg[i] : 0;
  int x = v;
#pragma unroll
  for (int off=1; off<64; off<<=1){
    const int y = __shfl_up(x, off, 64);
    if (l >= off) x += y;
  }
  if (l == 63) ws[wid] = x;
  __syncthreads();
  if (t == 0){
    int run = 0;
#pragma unroll
    for (int k=0;k<16;++k){ const int tmp = ws[k]; ws[k] = run; run += tmp; }
  }
  __syncthreads();
  if (i < NN){
    const int excl = boff[blockIdx.x] + ws[wid] + (x - v);
    rowptr[i] = excl; fillptr[i] = excl;
  }
  if (blockIdx.x == 0 && t == 0) rowptr[NN] = *total;
}

__global__ void k_fill(const int* __restrict__ dst, const int* __restrict__ src,
                       int* __restrict__ fillptr,
                       int* __restrict__ eid, int* __restrict__ srcc){
  for (int i = blockIdx.x*blockDim.x + threadIdx.x; i < NE; i += gridDim.x*blockDim.x){
    const int p = atomicAdd(&fillptr[dst[i]], 1);
    eid[p] = i;
    srcc[p] = src[i];
  }
}

// ---------- fused edge MLP -> ee (edge order; LDS-staged fully-coalesced writes) ----------
__global__ __launch_bounds__(256, 6) void k_edge(
    const float* __restrict__ efeat, const float* __restrict__ rij,
    const short* __restrict__ we1b, const float* __restrict__ be1,
    const short* __restrict__ we2b, const float* __restrict__ be2,
    const float* __restrict__ attn_e,
    float* __restrict__ ee)
{
  __shared__ __align__(16) short X[64*40];
  __shared__ float fc[64];
  __shared__ __align__(16) float eesh[64][8];
  const int e0 = blockIdx.x * 64;
  const int tid = threadIdx.x;
  const int w = tid >> 6, l = tid & 63, l15 = l & 15, lq = l >> 4;

  if (tid < 64){
    const float r = rij[e0 + tid];
    fc[tid] = (r < 5.0f) ? 0.5f*(__cosf(0.62831853071795864f*r) + 1.0f) : 0.0f;
  }

  // GEMM1: hoist all 8 efeat float4 loads (8 outstanding vmem), then convert+mfma
  const float* erow = efeat + (size_t)(e0 + w*16 + l15)*KIN + lq*8;
  float4 raw[4][2];
#pragma unroll
  for (int ks=0; ks<4; ++ks){
    raw[ks][0] = *reinterpret_cast<const float4*>(erow + ks*32);
    raw[ks][1] = *reinterpret_cast<const float4*>(erow + ks*32 + 4);
  }

  f32x4 acc1[2];
  acc1[0] = (f32x4)0.0f; acc1[1] = (f32x4)0.0f;
#pragma unroll
  for (int ks=0; ks<4; ++ks){
    const int k0 = ks*32 + lq*8;
    bf16x8 af;
    af[0]=f2b(raw[ks][0].x); af[1]=f2b(raw[ks][0].y); af[2]=f2b(raw[ks][0].z); af[3]=f2b(raw[ks][0].w);
    af[4]=f2b(raw[ks][1].x); af[5]=f2b(raw[ks][1].y); af[6]=f2b(raw[ks][1].z); af[7]=f2b(raw[ks][1].w);
#pragma unroll
    for (int tc=0;tc<2;++tc){
      const bf16x8 bfrag = *reinterpret_cast<const bf16x8*>(we1b + (tc*16 + l15)*KIN + k0);
      acc1[tc] = __builtin_amdgcn_mfma_f32_16x16x32_bf16(af, bfrag, acc1[tc], 0,0,0);
    }
  }
#pragma unroll
  for (int tc=0;tc<2;++tc){
    const int c = tc*16 + l15;
    const float b1 = be1[c];
#pragma unroll
    for (int j=0;j<4;++j){
      const int row = w*16 + lq*4 + j;
      X[row*40 + c] = f2b(sspf(acc1[tc][j] + b1));
    }
  }
  __syncthreads();

  // GEMM2 swapped: wave w owns channels [w*64, w*64+64) = heads 2w, 2w+1
  bf16x8 xfrag[4];
  float fcr[4];
#pragma unroll
  for (int cb=0;cb<4;++cb){
    xfrag[cb] = *reinterpret_cast<const bf16x8*>(&X[(cb*16 + l15)*40 + lq*8]);
    fcr[cb] = fc[cb*16 + l15];
  }

  float pe[4][2];
#pragma unroll
  for (int cb=0;cb<4;++cb){ pe[cb][0]=0.f; pe[cb][1]=0.f; }

#pragma unroll
  for (int rah=0; rah<2; ++rah){   // channel half = head w*2+rah
    f32x4 acc2[2][4];
#pragma unroll
    for (int r2=0;r2<2;++r2)
#pragma unroll
      for (int cb=0;cb<4;++cb) acc2[r2][cb] = (f32x4)0.0f;
    bf16x8 wfr[2];
#pragma unroll
    for (int r2=0;r2<2;++r2){
      const int ch = w*64 + (rah*2 + r2)*16 + l15;
      wfr[r2] = *reinterpret_cast<const bf16x8*>(we2b + ch*32 + lq*8);
    }
#pragma unroll
    for (int r2=0;r2<2;++r2)
#pragma unroll
      for (int cb=0;cb<4;++cb)
        acc2[r2][cb] = __builtin_amdgcn_mfma_f32_16x16x32_bf16(wfr[r2], xfrag[cb], acc2[r2][cb], 0,0,0);

#pragma unroll
    for (int r2=0;r2<2;++r2){
      const int ra = rah*2 + r2;
      const int cbase = w*64 + ra*16 + lq*4;
      const f32x4 b2v = *reinterpret_cast<const f32x4*>(be2 + cbase);
      const f32x4 aev = *reinterpret_cast<const f32x4*>(attn_e + cbase);
#pragma unroll
      for (int cb=0;cb<4;++cb){
#pragma unroll
        for (int j=0;j<4;++j){
          const float v = sspf(acc2[r2][cb][j] + b2v[j]);
          pe[cb][rah] += v * aev[j];
        }
      }
    }
  }
  // reduce over lq (lane bits 4,5)
#pragma unroll
  for (int cb=0;cb<4;++cb){
    pe[cb][0] += __shfl_xor(pe[cb][0], 16, 64);
    pe[cb][1] += __shfl_xor(pe[cb][1], 16, 64);
    pe[cb][0] += __shfl_xor(pe[cb][0], 32, 64);
    pe[cb][1] += __shfl_xor(pe[cb][1], 32, 64);
  }
  if (lq == 0){
#pragma unroll
    for (int cb=0;cb<4;++cb){
      eesh[cb*16 + l15][2*w + 0] = pe[cb][0] * fcr[cb];
      eesh[cb*16 + l15][2*w + 1] = pe[cb][1] * fcr[cb];
    }
  }
  __syncthreads();
  // fully-coalesced 2KB burst: 256 threads x float2
  reinterpret_cast<float2*>(ee + (size_t)e0*8)[tid] =
      reinterpret_cast<const float2*>(&eesh[0][0])[tid];
}

// ---------- fused softmax + aggregation: block per node ----------
__global__ __launch_bounds__(256) void k_sa(
    const int* __restrict__ rowptr, const int* __restrict__ eid,
    const int* __restrict__ srcc,
    const float* __restrict__ el, const float* __restrict__ er,
    const float* __restrict__ ee, const short* __restrict__ featb,
    const float* __restrict__ bias, float* __restrict__ coefg,
    float* __restrict__ out)
{
  __shared__ __align__(16) float cf[DMAX][8];
  __shared__ float red[4][32][8];
  const int n = blockIdx.x;
  const int t = threadIdx.x;
  const int beg = rowptr[n], end = rowptr[n+1];
  const int deg = end - beg;
  const bool inlds = (deg <= DMAX);

  if (t < 64){
    const int l = t;
    const f32x4 er0 = *reinterpret_cast<const f32x4*>(er + (size_t)n*8);
    const f32x4 er1 = *reinterpret_cast<const f32x4*>(er + (size_t)n*8 + 4);
    if (deg <= 64){
      const int p = beg + l;
      const bool v = p < end;
      f32x4 e0v=(f32x4)0.f, e1v=(f32x4)0.f;
      f32x4 x0=(f32x4)(-3e38f), x1=(f32x4)(-3e38f);
      if (v){
        const int id = eid[p], s = srcc[p];
        e0v = *reinterpret_cast<const f32x4*>(ee + (size_t)id*8);
        e1v = *reinterpret_cast<const f32x4*>(ee + (size_t)id*8 + 4);
        const f32x4 l0 = *reinterpret_cast<const f32x4*>(el + (size_t)s*8);
        const f32x4 l1 = *reinterpret_cast<const f32x4*>(el + (size_t)s*8 + 4);
        x0 = leaky4(e0v + l0 + er0);
        x1 = leaky4(e1v + l1 + er1);
      }
      f32x4 m0 = x0, m1 = x1;
#pragma unroll
      for (int m=1;m<64;m<<=1){
#pragma unroll
        for (int k=0;k<4;++k){
          m0[k] = fmaxf(m0[k], __shfl_xor(m0[k], m, 64));
          m1[k] = fmaxf(m1[k], __shfl_xor(m1[k], m, 64));
        }
      }
      const f32x4 p0 = exp4(x0 - m0), p1 = exp4(x1 - m1);
      f32x4 s0 = p0, s1 = p1;
#pragma unroll
      for (int m=1;m<64;m<<=1){
#pragma unroll
        for (int k=0;k<4;++k){
          s0[k] += __shfl_xor(s0[k], m, 64);
          s1[k] += __shfl_xor(s1[k], m, 64);
        }
      }
      f32x4 i0, i1;
#pragma unroll
      for (int k=0;k<4;++k){ i0[k] = 1.0f/s0[k]; i1[k] = 1.0f/s1[k]; }
      if (v){
        *reinterpret_cast<f32x4*>(&cf[l][0]) = p0 * i0 * e0v;
        *reinterpret_cast<f32x4*>(&cf[l][4]) = p1 * i1 * e1v;
      }
    } else {
      // generic 3-pass (rare)
      f32x4 m0 = (f32x4)(-3e38f), m1 = (f32x4)(-3e38f);
      for (int p = beg + l; p < end; p += 64){
        const int id = eid[p], s = srcc[p];
        const f32x4 e0v = *reinterpret_cast<const f32x4*>(ee + (size_t)id*8);
        const f32x4 e1v = *reinterpret_cast<const f32x4*>(ee + (size_t)id*8 + 4);
        const f32x4 l0 = *reinterpret_cast<const f32x4*>(el + (size_t)s*8);
        const f32x4 l1 = *reinterpret_cast<const f32x4*>(el + (size_t)s*8 + 4);
        m0 = max4(m0, leaky4(e0v + l0 + er0));
        m1 = max4(m1, leaky4(e1v + l1 + er1));
      }
#pragma unroll
      for (int m=1;m<64;m<<=1){
#pragma unroll
        for (int k=0;k<4;++k){
          m0[k] = fmaxf(m0[k], __shfl_xor(m0[k], m, 64));
          m1[k] = fmaxf(m1[k], __shfl_xor(m1[k], m, 64));
        }
      }
      f32x4 s0 = (f32x4)0.0f, s1 = (f32x4)0.0f;
      for (int p = beg + l; p < end; p += 64){
        const int id = eid[p], s = srcc[p];
        const f32x4 e0v = *reinterpret_cast<const f32x4*>(ee + (size_t)id*8);
        const f32x4 e1v = *reinterpret_cast<const f32x4*>(ee + (size_t)id*8 + 4);
        const f32x4 l0 = *reinterpret_cast<const f32x4*>(el + (size_t)s*8);
        const f32x4 l1 = *reinterpret_cast<const f32x4*>(el + (size_t)s*8 + 4);
        s0 += exp4(leaky4(e0v + l0 + er0) - m0);
        s1 += exp4(leaky4(e1v + l1 + er1) - m1);
      }
#pragma unroll
      for (int m=1;m<64;m<<=1){
#pragma unroll
        for (int k=0;k<4;++k){
          s0[k] += __shfl_xor(s0[k], m, 64);
          s1[k] += __shfl_xor(s1[k], m, 64);
        }
      }
      f32x4 i0, i1;
#pragma unroll
      for (int k=0;k<4;++k){ i0[k] = 1.0f/s0[k]; i1[k] = 1.0f/s1[k]; }
      for (int p = beg + l; p < end; p += 64){
        const int id = eid[p], s = srcc[p];
        const f32x4 e0v = *reinterpret_cast<const f32x4*>(ee + (size_t)id*8);
        const f32x4 e1v = *reinterpret_cast<const f32x4*>(ee + (size_t)id*8 + 4);
        const f32x4 l0 = *reinterpret_cast<const f32x4*>(el + (size_t)s*8);
        const f32x4 l1 = *reinterpret_cast<const f32x4*>(el + (size_t)s*8 + 4);
        const f32x4 o0 = exp4(leaky4(e0v + l0 + er0) - m0) * i0 * e0v;
        const f32x4 o1 = exp4(leaky4(e1v + l1 + er1) - m1) * i1 * e1v;
        if (inlds){
          *reinterpret_cast<f32x4*>(&cf[p-beg][0]) = o0;
          *reinterpret_cast<f32x4*>(&cf[p-beg][4]) = o1;
        } else {
          *reinterpret_cast<f32x4*>(coefg + (size_t)p*8) = o0;
          *reinterpret_cast<f32x4*>(coefg + (size_t)p*8 + 4) = o1;
        }
      }
    }
  }
  __syncthreads();

  // aggregation: 4 waves x 2 halves = 8 edges in flight
  const int l = t & 63, w = t >> 6;
  const int half = l >> 5, cl = l & 31;
  const int h = cl >> 2;
  float acc[8];
#pragma unroll
  for (int k=0;k<8;++k) acc[k] = 0.f;
  for (int p = beg + w*2 + half; p < end; p += 8){
    const int s = srcc[p];
    const float c = inlds ? cf[p-beg][h] : coefg[(size_t)p*8 + h];
    const short8v fv = *reinterpret_cast<const short8v*>(featb + (size_t)s*HD + cl*8);
#pragma unroll
    for (int k=0;k<8;++k) acc[k] += c * b2f(fv[k]);
  }
#pragma unroll
  for (int k=0;k<8;++k) acc[k] += __shfl_xor(acc[k], 32, 64);
  if (half == 0){
#pragma unroll
    for (int k=0;k<8;++k) red[w][cl][k] = acc[k];
  }
  __syncthreads();
  {
    const int cl2 = t >> 3, k2 = t & 7;
    out[(size_t)n*HD + t] = red[0][cl2][k2] + red[1][cl2][k2] + red[2][cl2][k2]
                          + red[3][cl2][k2] + bias[t];
  }
}

extern "C" void kernel_launch(void* const* d_in, const int* in_sizes, int n_in,
                              void* d_out, int out_size, void* d_ws, size_t ws_size,
                              hipStream_t stream) {
  const float* nfeat  = (const float*)d_in[0];
  const float* efeat  = (const float*)d_in[1];
  const float* rij    = (const float*)d_in[2];
  const int*   src    = (const int*)d_in[3];
  const int*   dst    = (const int*)d_in[4];
  const float* W_fc   = (const float*)d_in[5];
  const float* W_e1   = (const float*)d_in[6];
  const float* b_e1   = (const float*)d_in[7];
  const float* W_e2   = (const float*)d_in[8];
  const float* b_e2   = (const float*)d_in[9];
  const float* attn_l = (const float*)d_in[10];
  const float* attn_r = (const float*)d_in[11];
  const float* attn_e = (const float*)d_in[12];
  const float* bias   = (const float*)d_in[13];
  float* out = (float*)d_out;

  size_t off = 0;
  auto carve = [&](size_t nbytes) -> void* {
    void* p = (char*)d_ws + off;
    off += (nbytes + 255) & ~(size_t)255;
    return p;
  };
  short* featb = (short*)carve((size_t)NN*HD*2);
  float* el    = (float*)carve((size_t)NN*8*4);
  float* er    = (float*)carve((size_t)NN*8*4);
  float* ee    = (float*)carve((size_t)NE*8*4);
  float* coefg = (float*)carve((size_t)NE*8*4);
  int* deg     = (int*)carve((size_t)NN*4);
  int* rowptr  = (int*)carve((size_t)(NN+1)*4);
  int* fillptr = (int*)carve((size_t)(NN+1)*4);
  int* eidb    = (int*)carve((size_t)NE*4);
  int* srcc    = (int*)carve((size_t)NE*4);
  int* bsum    = (int*)carve((size_t)SCAN_B*4);
  int* boff    = (int*)carve((size_t)SCAN_B*4);
  int* total   = (int*)carve(4);
  short* wfcb  = (short*)carve((size_t)HD*KIN*2);
  short* we1b  = (short*)carve((size_t)32*KIN*2);
  short* we2b  = (short*)carve((size_t)HD*32*2);

  hipMemsetAsync(deg, 0, (size_t)NN*4, stream);
  k_convert<<<128, 256, 0, stream>>>(W_fc, W_e1, W_e2, wfcb, we1b, we2b);
  k_feat<<<(NN+63)/64, 256, 0, stream>>>(nfeat, wfcb, attn_l, attn_r, featb, el, er);
  k_hist<<<1024, 256, 0, stream>>>(dst, deg);
  k_scanA<<<SCAN_B, 1024, 0, stream>>>(deg, bsum);
  k_scanB<<<1, 64, 0, stream>>>(bsum, boff, total);
  k_scanC<<<SCAN_B, 1024, 0, stream>>>(deg, boff, total, rowptr, fillptr);
  k_fill<<<1024, 256, 0, stream>>>(dst, src, fillptr, eidb, srcc);
  k_edge<<<NE/64, 256, 0, stream>>>(efeat, rij, we1b, b_e1, we2b, b_e2, attn_e, ee);
  k_sa<<<NN, 256, 0, stream>>>(rowptr, eidb, srcc, el, er, ee, featb, bias, coefg, out);
}

// Round 6
// 450.935 us; speedup vs baseline: 1.4548x; 1.4548x over previous
//
#include <hip/hip_runtime.h>
#include <hip/hip_bf16.h>

#define NN 50000
#define NE 800000
#define HD 256
#define KIN 128
#define SCAN_B 49

typedef __attribute__((ext_vector_type(8))) short bf16x8;
typedef __attribute__((ext_vector_type(8))) short short8v;
typedef __attribute__((ext_vector_type(4))) float f32x4;

static __device__ __forceinline__ short f2b(float f){
  union { __hip_bfloat16 h; short s; } u;
  u.h = __float2bfloat16(f);
  return u.s;
}
static __device__ __forceinline__ float b2f(short s){
  union { __hip_bfloat16 h; short s; } u;
  u.s = s;
  return __bfloat162float(u.h);
}
// softplus(x) - log(2), hw transcendentals
static __device__ __forceinline__ float sspf(float x){
  const float t = __expf(-fabsf(x));
  return fmaxf(x, 0.0f) + __logf(1.0f + t) - 0.69314718055994531f;
}
static __device__ __forceinline__ f32x4 leaky4(f32x4 x){
  f32x4 r;
#pragma unroll
  for (int k=0;k<4;++k) r[k] = x[k] > 0.f ? x[k] : 0.2f*x[k];
  return r;
}
static __device__ __forceinline__ f32x4 max4(f32x4 a, f32x4 b){
  f32x4 r;
#pragma unroll
  for (int k=0;k<4;++k) r[k] = fmaxf(a[k], b[k]);
  return r;
}
static __device__ __forceinline__ f32x4 exp4(f32x4 x){
  f32x4 r;
#pragma unroll
  for (int k=0;k<4;++k) r[k] = __expf(x[k]);
  return r;
}

// ---------- weight fp32 -> bf16 ----------
__global__ void k_convert(const float* __restrict__ wfc, const float* __restrict__ we1,
                          const float* __restrict__ we2,
                          short* __restrict__ wfcb, short* __restrict__ we1b,
                          short* __restrict__ we2b){
  const int i = blockIdx.x*256 + threadIdx.x;
  if (i < HD*KIN) wfcb[i] = f2b(wfc[i]);
  if (i < 32*KIN) we1b[i] = f2b(we1[i]);
  if (i < HD*32)  we2b[i] = f2b(we2[i]);
}

// ---------- feat = nfeat @ W_fc^T  (+ el, er) ----------
__global__ __launch_bounds__(256) void k_feat(
    const float* __restrict__ nfeat, const short* __restrict__ wfcb,
    const float* __restrict__ attn_l, const float* __restrict__ attn_r,
    short* __restrict__ featb, float* __restrict__ el, float* __restrict__ er)
{
  const int n0 = blockIdx.x * 64;
  const int tid = threadIdx.x;
  const int w = tid >> 6, l = tid & 63, l15 = l & 15, lq = l >> 4;

  f32x4 acc[4][4];
#pragma unroll
  for (int a=0;a<4;++a)
#pragma unroll
    for (int b=0;b<4;++b) acc[a][b] = (f32x4)0.0f;

#pragma unroll
  for (int ks=0; ks<4; ++ks){
    const int k0 = ks*32 + lq*8;
    bf16x8 af[4];
#pragma unroll
    for (int tr=0; tr<4; ++tr){
      int row = n0 + tr*16 + l15;
      if (row >= NN) row = NN-1;
      const float4 x0 = *reinterpret_cast<const float4*>(nfeat + (size_t)row*KIN + k0);
      const float4 x1 = *reinterpret_cast<const float4*>(nfeat + (size_t)row*KIN + k0 + 4);
      af[tr][0]=f2b(x0.x); af[tr][1]=f2b(x0.y); af[tr][2]=f2b(x0.z); af[tr][3]=f2b(x0.w);
      af[tr][4]=f2b(x1.x); af[tr][5]=f2b(x1.y); af[tr][6]=f2b(x1.z); af[tr][7]=f2b(x1.w);
    }
#pragma unroll
    for (int tc=0; tc<4; ++tc){
      const int c = w*64 + tc*16 + l15;
      const bf16x8 bfrag = *reinterpret_cast<const bf16x8*>(wfcb + c*KIN + k0);
#pragma unroll
      for (int tr=0; tr<4; ++tr)
        acc[tr][tc] = __builtin_amdgcn_mfma_f32_16x16x32_bf16(af[tr], bfrag, acc[tr][tc], 0,0,0);
    }
  }

  float alr[4], arr_[4];
#pragma unroll
  for (int tc=0;tc<4;++tc){
    const int c = w*64 + tc*16 + l15;
    alr[tc] = attn_l[c]; arr_[tc] = attn_r[c];
  }
  float pl[4][4][2], pr[4][4][2];
#pragma unroll
  for (int tr=0;tr<4;++tr)
#pragma unroll
    for (int j=0;j<4;++j){ pl[tr][j][0]=pl[tr][j][1]=0.f; pr[tr][j][0]=pr[tr][j][1]=0.f; }

#pragma unroll
  for (int tr=0;tr<4;++tr){
    const int rowb = tr*16 + lq*4;
#pragma unroll
    for (int tc=0;tc<4;++tc){
      const int c = w*64 + tc*16 + l15;
      const int h2 = tc>>1;
#pragma unroll
      for (int j=0;j<4;++j){
        const float v = acc[tr][tc][j];
        const int node = n0 + rowb + j;
        if (node < NN) featb[node*HD + c] = f2b(v);
        pl[tr][j][h2] += v*alr[tc];
        pr[tr][j][h2] += v*arr_[tc];
      }
    }
  }
#pragma unroll
  for (int m=1;m<16;m<<=1){
#pragma unroll
    for (int tr=0;tr<4;++tr)
#pragma unroll
      for (int j=0;j<4;++j){
        pl[tr][j][0] += __shfl_xor(pl[tr][j][0], m, 64);
        pl[tr][j][1] += __shfl_xor(pl[tr][j][1], m, 64);
        pr[tr][j][0] += __shfl_xor(pr[tr][j][0], m, 64);
        pr[tr][j][1] += __shfl_xor(pr[tr][j][1], m, 64);
      }
  }
#pragma unroll
  for (int tr=0;tr<4;++tr)
#pragma unroll
    for (int j=0;j<4;++j)
      if (l15 == tr*4+j){
        const int node = n0 + tr*16 + lq*4 + j;
        if (node < NN){
          el[node*8 + 2*w + 0] = pl[tr][j][0];
          el[node*8 + 2*w + 1] = pl[tr][j][1];
          er[node*8 + 2*w + 0] = pr[tr][j][0];
          er[node*8 + 2*w + 1] = pr[tr][j][1];
        }
      }
}

// ---------- CSR build ----------
__global__ void k_hist(const int* __restrict__ dst, int* __restrict__ deg){
  for (int i = blockIdx.x*blockDim.x + threadIdx.x; i < NE; i += gridDim.x*blockDim.x)
    atomicAdd(&deg[dst[i]], 1);
}

__global__ __launch_bounds__(1024) void k_scanA(const int* __restrict__ deg,
                                                int* __restrict__ bsum){
  __shared__ int ws[16];
  const int t = threadIdx.x;
  const int i = blockIdx.x*1024 + t;
  int v = (i < NN) ? deg[i] : 0;
#pragma unroll
  for (int m=1;m<64;m<<=1) v += __shfl_xor(v, m, 64);
  if ((t & 63) == 0) ws[t >> 6] = v;
  __syncthreads();
  if (t == 0){
    int s = 0;
#pragma unroll
    for (int k=0;k<16;++k) s += ws[k];
    bsum[blockIdx.x] = s;
  }
}
__global__ void k_scanB(const int* __restrict__ bsum, int* __restrict__ boff,
                        int* __restrict__ total){
  const int t = threadIdx.x;  // 64 threads
  const int v = (t < SCAN_B) ? bsum[t] : 0;
  int x = v;
#pragma unroll
  for (int off=1; off<64; off<<=1){
    const int y = __shfl_up(x, off, 64);
    if (t >= off) x += y;
  }
  if (t < SCAN_B) boff[t] = x - v;
  if (t == 63) *total = x;
}
__global__ __launch_bounds__(1024) void k_scanC(const int* __restrict__ deg,
                                                const int* __restrict__ boff,
                                                const int* __restrict__ total,
                                                int* __restrict__ rowptr,
                                                int* __restrict__ fillptr){
  __shared__ int ws[16];
  const int t = threadIdx.x, l = t & 63, wid = t >> 6;
  const int i = blockIdx.x*1024 + t;
  const int v = (i < NN) ? deg[i] : 0;
  int x = v;
#pragma unroll
  for (int off=1; off<64; off<<=1){
    const int y = __shfl_up(x, off, 64);
    if (l >= off) x += y;
  }
  if (l == 63) ws[wid] = x;
  __syncthreads();
  if (t == 0){
    int run = 0;
#pragma unroll
    for (int k=0;k<16;++k){ const int tmp = ws[k]; ws[k] = run; run += tmp; }
  }
  __syncthreads();
  if (i < NN){
    const int excl = boff[blockIdx.x] + ws[wid] + (x - v);
    rowptr[i] = excl; fillptr[i] = excl;
  }
  if (blockIdx.x == 0 && t == 0) rowptr[NN] = *total;
}

__global__ void k_fill(const int* __restrict__ dst, const int* __restrict__ src,
                       int* __restrict__ fillptr,
                       int* __restrict__ eid, int* __restrict__ srcc){
  for (int i = blockIdx.x*blockDim.x + threadIdx.x; i < NE; i += gridDim.x*blockDim.x){
    const int p = atomicAdd(&fillptr[dst[i]], 1);
    eid[p] = i;
    srcc[p] = src[i];
  }
}

// ---------- fused edge MLP -> ee (edge order; hoisted loads, LDS-staged write) ----------
__global__ __launch_bounds__(256) void k_edge(
    const float* __restrict__ efeat, const float* __restrict__ rij,
    const short* __restrict__ we1b, const float* __restrict__ be1,
    const short* __restrict__ we2b, const float* __restrict__ be2,
    const float* __restrict__ attn_e,
    float* __restrict__ ee)
{
  __shared__ __align__(16) short X[64*40];
  __shared__ float fc[64];
  __shared__ __align__(16) float eesh[64][8];
  const int e0 = blockIdx.x * 64;
  const int tid = threadIdx.x;
  const int w = tid >> 6, l = tid & 63, l15 = l & 15, lq = l >> 4;

  // hoist ALL 8 efeat float4 loads -> 8 outstanding vmem before any dependent op
  const float* erow = efeat + (size_t)(e0 + w*16 + l15)*KIN + lq*8;
  const float4 r0 = *reinterpret_cast<const float4*>(erow);
  const float4 r1 = *reinterpret_cast<const float4*>(erow + 4);
  const float4 r2 = *reinterpret_cast<const float4*>(erow + 32);
  const float4 r3 = *reinterpret_cast<const float4*>(erow + 36);
  const float4 r4 = *reinterpret_cast<const float4*>(erow + 64);
  const float4 r5 = *reinterpret_cast<const float4*>(erow + 68);
  const float4 r6 = *reinterpret_cast<const float4*>(erow + 96);
  const float4 r7 = *reinterpret_cast<const float4*>(erow + 100);

  if (tid < 64){
    const float r = rij[e0 + tid];
    fc[tid] = (r < 5.0f) ? 0.5f*(__cosf(0.62831853071795864f*r) + 1.0f) : 0.0f;
  }

  f32x4 acc1[2];
  acc1[0] = (f32x4)0.0f; acc1[1] = (f32x4)0.0f;
  float4 raw[8] = {r0,r1,r2,r3,r4,r5,r6,r7};
#pragma unroll
  for (int ks=0; ks<4; ++ks){
    const int k0 = ks*32 + lq*8;
    bf16x8 af;
    af[0]=f2b(raw[2*ks].x); af[1]=f2b(raw[2*ks].y); af[2]=f2b(raw[2*ks].z); af[3]=f2b(raw[2*ks].w);
    af[4]=f2b(raw[2*ks+1].x); af[5]=f2b(raw[2*ks+1].y); af[6]=f2b(raw[2*ks+1].z); af[7]=f2b(raw[2*ks+1].w);
#pragma unroll
    for (int tc=0;tc<2;++tc){
      const bf16x8 bfrag = *reinterpret_cast<const bf16x8*>(we1b + (tc*16 + l15)*KIN + k0);
      acc1[tc] = __builtin_amdgcn_mfma_f32_16x16x32_bf16(af, bfrag, acc1[tc], 0,0,0);
    }
  }
#pragma unroll
  for (int tc=0;tc<2;++tc){
    const int c = tc*16 + l15;
    const float b1 = be1[c];
#pragma unroll
    for (int j=0;j<4;++j){
      const int row = w*16 + lq*4 + j;
      X[row*40 + c] = f2b(sspf(acc1[tc][j] + b1));
    }
  }
  __syncthreads();

  // GEMM2 swapped: wave w owns channels [w*64, w*64+64) = heads 2w, 2w+1
  bf16x8 xfrag[4];
  float fcr[4];
#pragma unroll
  for (int cb=0;cb<4;++cb){
    xfrag[cb] = *reinterpret_cast<const bf16x8*>(&X[(cb*16 + l15)*40 + lq*8]);
    fcr[cb] = fc[cb*16 + l15];
  }

  float pe[4][2];
#pragma unroll
  for (int cb=0;cb<4;++cb){ pe[cb][0]=0.f; pe[cb][1]=0.f; }

#pragma unroll
  for (int rah=0; rah<2; ++rah){   // channel half = head w*2+rah
    f32x4 acc2[2][4];
#pragma unroll
    for (int r2=0;r2<2;++r2)
#pragma unroll
      for (int cb=0;cb<4;++cb) acc2[r2][cb] = (f32x4)0.0f;
    bf16x8 wfr[2];
#pragma unroll
    for (int r2=0;r2<2;++r2){
      const int ch = w*64 + (rah*2 + r2)*16 + l15;
      wfr[r2] = *reinterpret_cast<const bf16x8*>(we2b + ch*32 + lq*8);
    }
#pragma unroll
    for (int r2=0;r2<2;++r2)
#pragma unroll
      for (int cb=0;cb<4;++cb)
        acc2[r2][cb] = __builtin_amdgcn_mfma_f32_16x16x32_bf16(wfr[r2], xfrag[cb], acc2[r2][cb], 0,0,0);

#pragma unroll
    for (int r2=0;r2<2;++r2){
      const int ra = rah*2 + r2;
      const int cbase = w*64 + ra*16 + lq*4;
      const f32x4 b2v = *reinterpret_cast<const f32x4*>(be2 + cbase);
      const f32x4 aev = *reinterpret_cast<const f32x4*>(attn_e + cbase);
#pragma unroll
      for (int cb=0;cb<4;++cb){
#pragma unroll
        for (int j=0;j<4;++j){
          const float v = sspf(acc2[r2][cb][j] + b2v[j]);
          pe[cb][rah] += v * aev[j];
        }
      }
    }
  }
  // reduce over lq (lane bits 4,5)
#pragma unroll
  for (int cb=0;cb<4;++cb){
    pe[cb][0] += __shfl_xor(pe[cb][0], 16, 64);
    pe[cb][1] += __shfl_xor(pe[cb][1], 16, 64);
    pe[cb][0] += __shfl_xor(pe[cb][0], 32, 64);
    pe[cb][1] += __shfl_xor(pe[cb][1], 32, 64);
  }
  if (lq == 0){
#pragma unroll
    for (int cb=0;cb<4;++cb){
      eesh[cb*16 + l15][2*w + 0] = pe[cb][0] * fcr[cb];
      eesh[cb*16 + l15][2*w + 1] = pe[cb][1] * fcr[cb];
    }
  }
  __syncthreads();
  // fully-coalesced 2KB burst: 256 threads x float2
  reinterpret_cast<float2*>(ee + (size_t)e0*8)[tid] =
      reinterpret_cast<const float2*>(&eesh[0][0])[tid];
}

// ---------- edge softmax: single-pass in registers (deg<=32), 16 lanes/node ----------
__global__ __launch_bounds__(256) void k_softmax(
    const int* __restrict__ rowptr, const int* __restrict__ eid,
    const int* __restrict__ srcc,
    const float* __restrict__ el, const float* __restrict__ er,
    const float* __restrict__ ee, float* __restrict__ coef)
{
  const int node = blockIdx.x*16 + (threadIdx.x >> 4);
  const int l = threadIdx.x & 15;
  if (node >= NN) return;
  const int beg = rowptr[node], end = rowptr[node+1];
  const int deg = end - beg;
  if (deg <= 0) return;
  const f32x4 er0 = *reinterpret_cast<const f32x4*>(er + (size_t)node*8);
  const f32x4 er1 = *reinterpret_cast<const f32x4*>(er + (size_t)node*8 + 4);

  if (deg <= 32){
    const int pa = beg + l, pb = beg + 16 + l;
    const bool va = pa < end, vb = pb < end;
    f32x4 ea0=(f32x4)0.f, ea1=(f32x4)0.f, eb0=(f32x4)0.f, eb1=(f32x4)0.f;
    f32x4 xa0=(f32x4)(-3e38f), xa1=(f32x4)(-3e38f), xb0=(f32x4)(-3e38f), xb1=(f32x4)(-3e38f);
    if (va){
      const int id = eid[pa], s = srcc[pa];
      ea0 = *reinterpret_cast<const f32x4*>(ee + (size_t)id*8);
      ea1 = *reinterpret_cast<const f32x4*>(ee + (size_t)id*8 + 4);
      const f32x4 l0 = *reinterpret_cast<const f32x4*>(el + (size_t)s*8);
      const f32x4 l1 = *reinterpret_cast<const f32x4*>(el + (size_t)s*8 + 4);
      xa0 = leaky4(ea0 + l0 + er0);
      xa1 = leaky4(ea1 + l1 + er1);
    }
    if (vb){
      const int id = eid[pb], s = srcc[pb];
      eb0 = *reinterpret_cast<const f32x4*>(ee + (size_t)id*8);
      eb1 = *reinterpret_cast<const f32x4*>(ee + (size_t)id*8 + 4);
      const f32x4 l0 = *reinterpret_cast<const f32x4*>(el + (size_t)s*8);
      const f32x4 l1 = *reinterpret_cast<const f32x4*>(el + (size_t)s*8 + 4);
      xb0 = leaky4(eb0 + l0 + er0);
      xb1 = leaky4(eb1 + l1 + er1);
    }
    f32x4 m0 = max4(xa0, xb0), m1 = max4(xa1, xb1);
#pragma unroll
    for (int m=1;m<16;m<<=1){
#pragma unroll
      for (int k=0;k<4;++k){
        m0[k] = fmaxf(m0[k], __shfl_xor(m0[k], m, 64));
        m1[k] = fmaxf(m1[k], __shfl_xor(m1[k], m, 64));
      }
    }
    const f32x4 pa0 = exp4(xa0 - m0), pa1 = exp4(xa1 - m1);
    const f32x4 pb0 = exp4(xb0 - m0), pb1 = exp4(xb1 - m1);
    f32x4 s0 = pa0 + pb0, s1 = pa1 + pb1;
#pragma unroll
    for (int m=1;m<16;m<<=1){
#pragma unroll
      for (int k=0;k<4;++k){
        s0[k] += __shfl_xor(s0[k], m, 64);
        s1[k] += __shfl_xor(s1[k], m, 64);
      }
    }
    f32x4 i0, i1;
#pragma unroll
    for (int k=0;k<4;++k){ i0[k] = 1.0f/s0[k]; i1[k] = 1.0f/s1[k]; }
    if (va){
      *reinterpret_cast<f32x4*>(coef + (size_t)pa*8)     = pa0 * i0 * ea0;
      *reinterpret_cast<f32x4*>(coef + (size_t)pa*8 + 4) = pa1 * i1 * ea1;
    }
    if (vb){
      *reinterpret_cast<f32x4*>(coef + (size_t)pb*8)     = pb0 * i0 * eb0;
      *reinterpret_cast<f32x4*>(coef + (size_t)pb*8 + 4) = pb1 * i1 * eb1;
    }
  } else {
    f32x4 m0 = (f32x4)(-3e38f), m1 = (f32x4)(-3e38f);
    for (int p = beg + l; p < end; p += 16){
      const int id = eid[p], s = srcc[p];
      const f32x4 e0v = *reinterpret_cast<const f32x4*>(ee + (size_t)id*8);
      const f32x4 e1v = *reinterpret_cast<const f32x4*>(ee + (size_t)id*8 + 4);
      const f32x4 l0 = *reinterpret_cast<const f32x4*>(el + (size_t)s*8);
      const f32x4 l1 = *reinterpret_cast<const f32x4*>(el + (size_t)s*8 + 4);
      m0 = max4(m0, leaky4(e0v + l0 + er0));
      m1 = max4(m1, leaky4(e1v + l1 + er1));
    }
#pragma unroll
    for (int m=1;m<16;m<<=1){
#pragma unroll
      for (int k=0;k<4;++k){
        m0[k] = fmaxf(m0[k], __shfl_xor(m0[k], m, 64));
        m1[k] = fmaxf(m1[k], __shfl_xor(m1[k], m, 64));
      }
    }
    f32x4 s0 = (f32x4)0.0f, s1 = (f32x4)0.0f;
    for (int p = beg + l; p < end; p += 16){
      const int id = eid[p], s = srcc[p];
      const f32x4 e0v = *reinterpret_cast<const f32x4*>(ee + (size_t)id*8);
      const f32x4 e1v = *reinterpret_cast<const f32x4*>(ee + (size_t)id*8 + 4);
      const f32x4 l0 = *reinterpret_cast<const f32x4*>(el + (size_t)s*8);
      const f32x4 l1 = *reinterpret_cast<const f32x4*>(el + (size_t)s*8 + 4);
      s0 += exp4(leaky4(e0v + l0 + er0) - m0);
      s1 += exp4(leaky4(e1v + l1 + er1) - m1);
    }
#pragma unroll
    for (int m=1;m<16;m<<=1){
#pragma unroll
      for (int k=0;k<4;++k){
        s0[k] += __shfl_xor(s0[k], m, 64);
        s1[k] += __shfl_xor(s1[k], m, 64);
      }
    }
    f32x4 i0, i1;
#pragma unroll
    for (int k=0;k<4;++k){ i0[k] = 1.0f/s0[k]; i1[k] = 1.0f/s1[k]; }
    for (int p = beg + l; p < end; p += 16){
      const int id = eid[p], s = srcc[p];
      const f32x4 e0v = *reinterpret_cast<const f32x4*>(ee + (size_t)id*8);
      const f32x4 e1v = *reinterpret_cast<const f32x4*>(ee + (size_t)id*8 + 4);
      const f32x4 l0 = *reinterpret_cast<const f32x4*>(el + (size_t)s*8);
      const f32x4 l1 = *reinterpret_cast<const f32x4*>(el + (size_t)s*8 + 4);
      const f32x4 o0 = exp4(leaky4(e0v + l0 + er0) - m0) * i0 * e0v;
      const f32x4 o1 = exp4(leaky4(e1v + l1 + er1) - m1) * i1 * e1v;
      *reinterpret_cast<f32x4*>(coef + (size_t)p*8) = o0;
      *reinterpret_cast<f32x4*>(coef + (size_t)p*8 + 4) = o1;
    }
  }
}

// ---------- aggregation: block per node, 4 waves x 2 edges each in flight ----------
__global__ __launch_bounds__(256) void k_agg(
    const int* __restrict__ rowptr, const int* __restrict__ srcc,
    const float* __restrict__ coef, const short* __restrict__ featb,
    const float* __restrict__ bias, float* __restrict__ out)
{
  __shared__ float red[4][32][8];
  const int n = blockIdx.x;
  const int t = threadIdx.x, l = t & 63, w = t >> 6;
  const int half = l >> 5, cl = l & 31;      // channels cl*8..cl*8+7
  const int h = cl >> 2;                      // head for these channels
  const int beg = rowptr[n], end = rowptr[n+1];
  float acc[8];
#pragma unroll
  for (int k=0;k<8;++k) acc[k] = 0.f;
  for (int p = beg + w*2 + half; p < end; p += 8){
    const int s = srcc[p];
    const float cf = coef[(size_t)p*8 + h];
    const short8v fv = *reinterpret_cast<const short8v*>(featb + (size_t)s*HD + cl*8);
#pragma unroll
    for (int k=0;k<8;++k) acc[k] += cf * b2f(fv[k]);
  }
#pragma unroll
  for (int k=0;k<8;++k) acc[k] += __shfl_xor(acc[k], 32, 64);
  if (half == 0){
#pragma unroll
    for (int k=0;k<8;++k) red[w][cl][k] = acc[k];
  }
  __syncthreads();
  {
    const int cl2 = t >> 3, k2 = t & 7;
    out[(size_t)n*HD + t] = red[0][cl2][k2] + red[1][cl2][k2] + red[2][cl2][k2]
                          + red[3][cl2][k2] + bias[t];
  }
}

extern "C" void kernel_launch(void* const* d_in, const int* in_sizes, int n_in,
                              void* d_out, int out_size, void* d_ws, size_t ws_size,
                              hipStream_t stream) {
  const float* nfeat  = (const float*)d_in[0];
  const float* efeat  = (const float*)d_in[1];
  const float* rij    = (const float*)d_in[2];
  const int*   src    = (const int*)d_in[3];
  const int*   dst    = (const int*)d_in[4];
  const float* W_fc   = (const float*)d_in[5];
  const float* W_e1   = (const float*)d_in[6];
  const float* b_e1   = (const float*)d_in[7];
  const float* W_e2   = (const float*)d_in[8];
  const float* b_e2   = (const float*)d_in[9];
  const float* attn_l = (const float*)d_in[10];
  const float* attn_r = (const float*)d_in[11];
  const float* attn_e = (const float*)d_in[12];
  const float* bias   = (const float*)d_in[13];
  float* out = (float*)d_out;

  size_t off = 0;
  auto carve = [&](size_t nbytes) -> void* {
    void* p = (char*)d_ws + off;
    off += (nbytes + 255) & ~(size_t)255;
    return p;
  };
  short* featb = (short*)carve((size_t)NN*HD*2);
  float* el    = (float*)carve((size_t)NN*8*4);
  float* er    = (float*)carve((size_t)NN*8*4);
  float* ee    = (float*)carve((size_t)NE*8*4);
  float* coef  = (float*)carve((size_t)NE*8*4);
  int* deg     = (int*)carve((size_t)NN*4);
  int* rowptr  = (int*)carve((size_t)(NN+1)*4);
  int* fillptr = (int*)carve((size_t)(NN+1)*4);
  int* eidb    = (int*)carve((size_t)NE*4);
  int* srcc    = (int*)carve((size_t)NE*4);
  int* bsum    = (int*)carve((size_t)SCAN_B*4);
  int* boff    = (int*)carve((size_t)SCAN_B*4);
  int* total   = (int*)carve(4);
  short* wfcb  = (short*)carve((size_t)HD*KIN*2);
  short* we1b  = (short*)carve((size_t)32*KIN*2);
  short* we2b  = (short*)carve((size_t)HD*32*2);

  hipMemsetAsync(deg, 0, (size_t)NN*4, stream);
  k_convert<<<128, 256, 0, stream>>>(W_fc, W_e1, W_e2, wfcb, we1b, we2b);
  k_feat<<<(NN+63)/64, 256, 0, stream>>>(nfeat, wfcb, attn_l, attn_r, featb, el, er);
  k_hist<<<1024, 256, 0, stream>>>(dst, deg);
  k_scanA<<<SCAN_B, 1024, 0, stream>>>(deg, bsum);
  k_scanB<<<1, 64, 0, stream>>>(bsum, boff, total);
  k_scanC<<<SCAN_B, 1024, 0, stream>>>(deg, boff, total, rowptr, fillptr);
  k_fill<<<1024, 256, 0, stream>>>(dst, src, fillptr, eidb, srcc);
  k_edge<<<NE/64, 256, 0, stream>>>(efeat, rij, we1b, b_e1, we2b, b_e2, attn_e, ee);
  k_softmax<<<(NN+15)/16, 256, 0, stream>>>(rowptr, eidb, srcc, el, er, ee, coef);
  k_agg<<<NN, 256, 0, stream>>>(rowptr, srcc, coef, featb, bias, out);
}

// Round 7
// 448.474 us; speedup vs baseline: 1.4628x; 1.0055x over previous
//
#include <hip/hip_runtime.h>
#include <hip/hip_bf16.h>

#define NN 50000
#define NE 800000
#define HD 256
#define KIN 128
#define SCAN_B 49

typedef __attribute__((ext_vector_type(8))) short bf16x8;
typedef __attribute__((ext_vector_type(8))) short short8v;
typedef __attribute__((ext_vector_type(4))) float f32x4;

static __device__ __forceinline__ short f2b(float f){
  union { __hip_bfloat16 h; short s; } u;
  u.h = __float2bfloat16(f);
  return u.s;
}
static __device__ __forceinline__ float b2f(short s){
  union { __hip_bfloat16 h; short s; } u;
  u.s = s;
  return __bfloat162float(u.h);
}
static __device__ __forceinline__ unsigned packbf(float a, float b){
  union { short s[2]; unsigned u; } z;
  z.s[0] = f2b(a); z.s[1] = f2b(b);
  return z.u;
}
// softplus(x) - log(2), hw transcendentals
static __device__ __forceinline__ float sspf(float x){
  const float t = __expf(-fabsf(x));
  return fmaxf(x, 0.0f) + __logf(1.0f + t) - 0.69314718055994531f;
}
static __device__ __forceinline__ f32x4 leaky4(f32x4 x){
  f32x4 r;
#pragma unroll
  for (int k=0;k<4;++k) r[k] = x[k] > 0.f ? x[k] : 0.2f*x[k];
  return r;
}
static __device__ __forceinline__ f32x4 max4(f32x4 a, f32x4 b){
  f32x4 r;
#pragma unroll
  for (int k=0;k<4;++k) r[k] = fmaxf(a[k], b[k]);
  return r;
}
static __device__ __forceinline__ f32x4 exp4(f32x4 x){
  f32x4 r;
#pragma unroll
  for (int k=0;k<4;++k) r[k] = __expf(x[k]);
  return r;
}

// ---------- weight fp32 -> bf16 ----------
__global__ void k_convert(const float* __restrict__ wfc, const float* __restrict__ we1,
                          const float* __restrict__ we2,
                          short* __restrict__ wfcb, short* __restrict__ we1b,
                          short* __restrict__ we2b){
  const int i = blockIdx.x*256 + threadIdx.x;
  if (i < HD*KIN) wfcb[i] = f2b(wfc[i]);
  if (i < 32*KIN) we1b[i] = f2b(we1[i]);
  if (i < HD*32)  we2b[i] = f2b(we2[i]);
}

// ---------- feat = nfeat @ W_fc^T  (+ el, er) ----------
__global__ __launch_bounds__(256) void k_feat(
    const float* __restrict__ nfeat, const short* __restrict__ wfcb,
    const float* __restrict__ attn_l, const float* __restrict__ attn_r,
    short* __restrict__ featb, float* __restrict__ el, float* __restrict__ er)
{
  const int n0 = blockIdx.x * 64;
  const int tid = threadIdx.x;
  const int w = tid >> 6, l = tid & 63, l15 = l & 15, lq = l >> 4;

  f32x4 acc[4][4];
#pragma unroll
  for (int a=0;a<4;++a)
#pragma unroll
    for (int b=0;b<4;++b) acc[a][b] = (f32x4)0.0f;

#pragma unroll
  for (int ks=0; ks<4; ++ks){
    const int k0 = ks*32 + lq*8;
    bf16x8 af[4];
#pragma unroll
    for (int tr=0; tr<4; ++tr){
      int row = n0 + tr*16 + l15;
      if (row >= NN) row = NN-1;
      const float4 x0 = *reinterpret_cast<const float4*>(nfeat + (size_t)row*KIN + k0);
      const float4 x1 = *reinterpret_cast<const float4*>(nfeat + (size_t)row*KIN + k0 + 4);
      af[tr][0]=f2b(x0.x); af[tr][1]=f2b(x0.y); af[tr][2]=f2b(x0.z); af[tr][3]=f2b(x0.w);
      af[tr][4]=f2b(x1.x); af[tr][5]=f2b(x1.y); af[tr][6]=f2b(x1.z); af[tr][7]=f2b(x1.w);
    }
#pragma unroll
    for (int tc=0; tc<4; ++tc){
      const int c = w*64 + tc*16 + l15;
      const bf16x8 bfrag = *reinterpret_cast<const bf16x8*>(wfcb + c*KIN + k0);
#pragma unroll
      for (int tr=0; tr<4; ++tr)
        acc[tr][tc] = __builtin_amdgcn_mfma_f32_16x16x32_bf16(af[tr], bfrag, acc[tr][tc], 0,0,0);
    }
  }

  float alr[4], arr_[4];
#pragma unroll
  for (int tc=0;tc<4;++tc){
    const int c = w*64 + tc*16 + l15;
    alr[tc] = attn_l[c]; arr_[tc] = attn_r[c];
  }
  float pl[4][4][2], pr[4][4][2];
#pragma unroll
  for (int tr=0;tr<4;++tr)
#pragma unroll
    for (int j=0;j<4;++j){ pl[tr][j][0]=pl[tr][j][1]=0.f; pr[tr][j][0]=pr[tr][j][1]=0.f; }

#pragma unroll
  for (int tr=0;tr<4;++tr){
    const int rowb = tr*16 + lq*4;
#pragma unroll
    for (int tc=0;tc<4;++tc){
      const int c = w*64 + tc*16 + l15;
      const int h2 = tc>>1;
#pragma unroll
      for (int j=0;j<4;++j){
        const float v = acc[tr][tc][j];
        const int node = n0 + rowb + j;
        if (node < NN) featb[node*HD + c] = f2b(v);
        pl[tr][j][h2] += v*alr[tc];
        pr[tr][j][h2] += v*arr_[tc];
      }
    }
  }
#pragma unroll
  for (int m=1;m<16;m<<=1){
#pragma unroll
    for (int tr=0;tr<4;++tr)
#pragma unroll
      for (int j=0;j<4;++j){
        pl[tr][j][0] += __shfl_xor(pl[tr][j][0], m, 64);
        pl[tr][j][1] += __shfl_xor(pl[tr][j][1], m, 64);
        pr[tr][j][0] += __shfl_xor(pr[tr][j][0], m, 64);
        pr[tr][j][1] += __shfl_xor(pr[tr][j][1], m, 64);
      }
  }
#pragma unroll
  for (int tr=0;tr<4;++tr)
#pragma unroll
    for (int j=0;j<4;++j)
      if (l15 == tr*4+j){
        const int node = n0 + tr*16 + lq*4 + j;
        if (node < NN){
          el[node*8 + 2*w + 0] = pl[tr][j][0];
          el[node*8 + 2*w + 1] = pl[tr][j][1];
          er[node*8 + 2*w + 0] = pr[tr][j][0];
          er[node*8 + 2*w + 1] = pr[tr][j][1];
        }
      }
}

// ---------- CSR build ----------
__global__ void k_hist(const int* __restrict__ dst, int* __restrict__ deg){
  for (int i = blockIdx.x*blockDim.x + threadIdx.x; i < NE; i += gridDim.x*blockDim.x)
    atomicAdd(&deg[dst[i]], 1);
}

__global__ __launch_bounds__(1024) void k_scanA(const int* __restrict__ deg,
                                                int* __restrict__ bsum){
  __shared__ int ws[16];
  const int t = threadIdx.x;
  const int i = blockIdx.x*1024 + t;
  int v = (i < NN) ? deg[i] : 0;
#pragma unroll
  for (int m=1;m<64;m<<=1) v += __shfl_xor(v, m, 64);
  if ((t & 63) == 0) ws[t >> 6] = v;
  __syncthreads();
  if (t == 0){
    int s = 0;
#pragma unroll
    for (int k=0;k<16;++k) s += ws[k];
    bsum[blockIdx.x] = s;
  }
}
__global__ void k_scanB(const int* __restrict__ bsum, int* __restrict__ boff,
                        int* __restrict__ total){
  const int t = threadIdx.x;  // 64 threads
  const int v = (t < SCAN_B) ? bsum[t] : 0;
  int x = v;
#pragma unroll
  for (int off=1; off<64; off<<=1){
    const int y = __shfl_up(x, off, 64);
    if (t >= off) x += y;
  }
  if (t < SCAN_B) boff[t] = x - v;
  if (t == 63) *total = x;
}
__global__ __launch_bounds__(1024) void k_scanC(const int* __restrict__ deg,
                                                const int* __restrict__ boff,
                                                const int* __restrict__ total,
                                                int* __restrict__ rowptr,
                                                int* __restrict__ fillptr){
  __shared__ int ws[16];
  const int t = threadIdx.x, l = t & 63, wid = t >> 6;
  const int i = blockIdx.x*1024 + t;
  const int v = (i < NN) ? deg[i] : 0;
  int x = v;
#pragma unroll
  for (int off=1; off<64; off<<=1){
    const int y = __shfl_up(x, off, 64);
    if (l >= off) x += y;
  }
  if (l == 63) ws[wid] = x;
  __syncthreads();
  if (t == 0){
    int run = 0;
#pragma unroll
    for (int k=0;k<16;++k){ const int tmp = ws[k]; ws[k] = run; run += tmp; }
  }
  __syncthreads();
  if (i < NN){
    const int excl = boff[blockIdx.x] + ws[wid] + (x - v);
    rowptr[i] = excl; fillptr[i] = excl;
  }
  if (blockIdx.x == 0 && t == 0) rowptr[NN] = *total;
}

__global__ void k_fill(const int* __restrict__ dst, const int* __restrict__ src,
                       int* __restrict__ fillptr,
                       int* __restrict__ eid, int* __restrict__ srcc){
  for (int i = blockIdx.x*blockDim.x + threadIdx.x; i < NE; i += gridDim.x*blockDim.x){
    const int p = atomicAdd(&fillptr[dst[i]], 1);
    eid[p] = i;
    srcc[p] = src[i];
  }
}

// ---------- fused edge MLP -> ee: WAVE-INDEPENDENT, zero LDS, zero barriers ----------
// Each wave owns 16 edges. GEMM1 swapped: D[hidden, edge] so X stays in registers;
// lane permutation (8 shfl) re-lays X into the GEMM2 B-fragment; GEMM2 = 16 MFMA tiles.
__global__ __launch_bounds__(256) void k_edge(
    const float* __restrict__ efeat, const float* __restrict__ rij,
    const short* __restrict__ we1b, const float* __restrict__ be1,
    const short* __restrict__ we2b, const float* __restrict__ be2,
    const float* __restrict__ attn_e,
    float* __restrict__ ee)
{
  const int tid = threadIdx.x;
  const int w = tid >> 6, l = tid & 63, l15 = l & 15, lq = l >> 4;
  const int e0w = blockIdx.x * 64 + w * 16;   // this wave's 16 edges

  // hoist all 8 efeat float4 loads (8 outstanding vmem)
  const float* erow = efeat + (size_t)(e0w + l15)*KIN + lq*8;
  const float4 r0 = *reinterpret_cast<const float4*>(erow);
  const float4 r1 = *reinterpret_cast<const float4*>(erow + 4);
  const float4 r2 = *reinterpret_cast<const float4*>(erow + 32);
  const float4 r3 = *reinterpret_cast<const float4*>(erow + 36);
  const float4 r4 = *reinterpret_cast<const float4*>(erow + 64);
  const float4 r5 = *reinterpret_cast<const float4*>(erow + 68);
  const float4 r6 = *reinterpret_cast<const float4*>(erow + 96);
  const float4 r7 = *reinterpret_cast<const float4*>(erow + 100);
  const float rv = rij[e0w + l15];

  // GEMM1 swapped: A = W1[hidden th*16+l15][k], B = efeat[edge l15][k]
  // D_th[row=hidden th*16+lq*4+j][col=edge l15]
  f32x4 acc_t0 = (f32x4)0.0f, acc_t1 = (f32x4)0.0f;
  float4 raw[8] = {r0,r1,r2,r3,r4,r5,r6,r7};
#pragma unroll
  for (int ks=0; ks<4; ++ks){
    const int k0 = ks*32 + lq*8;
    bf16x8 bfr;
    bfr[0]=f2b(raw[2*ks].x); bfr[1]=f2b(raw[2*ks].y); bfr[2]=f2b(raw[2*ks].z); bfr[3]=f2b(raw[2*ks].w);
    bfr[4]=f2b(raw[2*ks+1].x); bfr[5]=f2b(raw[2*ks+1].y); bfr[6]=f2b(raw[2*ks+1].z); bfr[7]=f2b(raw[2*ks+1].w);
    const bf16x8 a0 = *reinterpret_cast<const bf16x8*>(we1b + (l15     )*KIN + k0);
    const bf16x8 a1 = *reinterpret_cast<const bf16x8*>(we1b + (16 + l15)*KIN + k0);
    acc_t0 = __builtin_amdgcn_mfma_f32_16x16x32_bf16(a0, bfr, acc_t0, 0,0,0);
    acc_t1 = __builtin_amdgcn_mfma_f32_16x16x32_bf16(a1, bfr, acc_t1, 0,0,0);
  }

  // bias + ssp; lane holds X[edge l15][hidden lq*4+j] (th0) and [16+lq*4+j] (th1)
  const f32x4 b1a = *reinterpret_cast<const f32x4*>(be1 + lq*4);
  const f32x4 b1b = *reinterpret_cast<const f32x4*>(be1 + 16 + lq*4);
  const unsigned t0lo = packbf(sspf(acc_t0[0]+b1a[0]), sspf(acc_t0[1]+b1a[1]));
  const unsigned t0hi = packbf(sspf(acc_t0[2]+b1a[2]), sspf(acc_t0[3]+b1a[3]));
  const unsigned t1lo = packbf(sspf(acc_t1[0]+b1b[0]), sspf(acc_t1[1]+b1b[1]));
  const unsigned t1hi = packbf(sspf(acc_t1[2]+b1b[2]), sspf(acc_t1[3]+b1b[3]));

  // permute to GEMM2 B-frag: lane needs X[edge l15][hidden lq*8 .. lq*8+7]
  const int srcA = ((lq & 1) << 5) + l15;   // lane (lq&1)*2, same l15
  const int srcB = srcA + 16;               // lane (lq&1)*2+1
  const int a_lo0 = __shfl((int)t0lo, srcA, 64), a_hi0 = __shfl((int)t0hi, srcA, 64);
  const int b_lo0 = __shfl((int)t0lo, srcB, 64), b_hi0 = __shfl((int)t0hi, srcB, 64);
  const int a_lo1 = __shfl((int)t1lo, srcA, 64), a_hi1 = __shfl((int)t1hi, srcA, 64);
  const int b_lo1 = __shfl((int)t1lo, srcB, 64), b_hi1 = __shfl((int)t1hi, srcB, 64);
  const bool th1sel = (lq & 2);
  union { int u[4]; bf16x8 v; } bx;
  bx.u[0] = th1sel ? a_lo1 : a_lo0;
  bx.u[1] = th1sel ? a_hi1 : a_hi0;
  bx.u[2] = th1sel ? b_lo1 : b_lo0;
  bx.u[3] = th1sel ? b_hi1 : b_hi0;

  // GEMM2: 16 channel tiles of 16; A = W2[ch cht*16+l15][hidden lq*8..+7], K=32 exact
  float pe[8];
#pragma unroll
  for (int h=0;h<8;++h) pe[h] = 0.f;
#pragma unroll
  for (int cht=0; cht<16; ++cht){
    const bf16x8 a2 = *reinterpret_cast<const bf16x8*>(we2b + (cht*16 + l15)*32 + lq*8);
    const f32x4 d = __builtin_amdgcn_mfma_f32_16x16x32_bf16(a2, bx.v, (f32x4)0.0f, 0,0,0);
    const f32x4 b2v = *reinterpret_cast<const f32x4*>(be2    + cht*16 + lq*4);
    const f32x4 aev = *reinterpret_cast<const f32x4*>(attn_e + cht*16 + lq*4);
    float s = 0.f;
#pragma unroll
    for (int j=0;j<4;++j) s += sspf(d[j] + b2v[j]) * aev[j];
    pe[cht>>1] += s;
  }
  // reduce over the 4 lq groups (full head sums in every lane)
#pragma unroll
  for (int h=0;h<8;++h){
    pe[h] += __shfl_xor(pe[h], 16, 64);
    pe[h] += __shfl_xor(pe[h], 32, 64);
  }
  const float fcv = (rv < 5.0f) ? 0.5f*(__cosf(0.62831853071795864f*rv) + 1.0f) : 0.0f;
  const float o0 = (lq==0) ? pe[0] : (lq==1) ? pe[2] : (lq==2) ? pe[4] : pe[6];
  const float o1 = (lq==0) ? pe[1] : (lq==1) ? pe[3] : (lq==2) ? pe[5] : pe[7];
  float2 outv; outv.x = o0*fcv; outv.y = o1*fcv;
  *reinterpret_cast<float2*>(ee + (size_t)(e0w + l15)*8 + lq*2) = outv;
}

// ---------- edge softmax: single-pass in registers (deg<=32), 16 lanes/node ----------
__global__ __launch_bounds__(256) void k_softmax(
    const int* __restrict__ rowptr, const int* __restrict__ eid,
    const int* __restrict__ srcc,
    const float* __restrict__ el, const float* __restrict__ er,
    const float* __restrict__ ee, float* __restrict__ coef)
{
  const int node = blockIdx.x*16 + (threadIdx.x >> 4);
  const int l = threadIdx.x & 15;
  if (node >= NN) return;
  const int beg = rowptr[node], end = rowptr[node+1];
  const int deg = end - beg;
  if (deg <= 0) return;
  const f32x4 er0 = *reinterpret_cast<const f32x4*>(er + (size_t)node*8);
  const f32x4 er1 = *reinterpret_cast<const f32x4*>(er + (size_t)node*8 + 4);

  if (deg <= 32){
    const int pa = beg + l, pb = beg + 16 + l;
    const bool va = pa < end, vb = pb < end;
    f32x4 ea0=(f32x4)0.f, ea1=(f32x4)0.f, eb0=(f32x4)0.f, eb1=(f32x4)0.f;
    f32x4 xa0=(f32x4)(-3e38f), xa1=(f32x4)(-3e38f), xb0=(f32x4)(-3e38f), xb1=(f32x4)(-3e38f);
    if (va){
      const int id = eid[pa], s = srcc[pa];
      ea0 = *reinterpret_cast<const f32x4*>(ee + (size_t)id*8);
      ea1 = *reinterpret_cast<const f32x4*>(ee + (size_t)id*8 + 4);
      const f32x4 l0 = *reinterpret_cast<const f32x4*>(el + (size_t)s*8);
      const f32x4 l1 = *reinterpret_cast<const f32x4*>(el + (size_t)s*8 + 4);
      xa0 = leaky4(ea0 + l0 + er0);
      xa1 = leaky4(ea1 + l1 + er1);
    }
    if (vb){
      const int id = eid[pb], s = srcc[pb];
      eb0 = *reinterpret_cast<const f32x4*>(ee + (size_t)id*8);
      eb1 = *reinterpret_cast<const f32x4*>(ee + (size_t)id*8 + 4);
      const f32x4 l0 = *reinterpret_cast<const f32x4*>(el + (size_t)s*8);
      const f32x4 l1 = *reinterpret_cast<const f32x4*>(el + (size_t)s*8 + 4);
      xb0 = leaky4(eb0 + l0 + er0);
      xb1 = leaky4(eb1 + l1 + er1);
    }
    f32x4 m0 = max4(xa0, xb0), m1 = max4(xa1, xb1);
#pragma unroll
    for (int m=1;m<16;m<<=1){
#pragma unroll
      for (int k=0;k<4;++k){
        m0[k] = fmaxf(m0[k], __shfl_xor(m0[k], m, 64));
        m1[k] = fmaxf(m1[k], __shfl_xor(m1[k], m, 64));
      }
    }
    const f32x4 pa0 = exp4(xa0 - m0), pa1 = exp4(xa1 - m1);
    const f32x4 pb0 = exp4(xb0 - m0), pb1 = exp4(xb1 - m1);
    f32x4 s0 = pa0 + pb0, s1 = pa1 + pb1;
#pragma unroll
    for (int m=1;m<16;m<<=1){
#pragma unroll
      for (int k=0;k<4;++k){
        s0[k] += __shfl_xor(s0[k], m, 64);
        s1[k] += __shfl_xor(s1[k], m, 64);
      }
    }
    f32x4 i0, i1;
#pragma unroll
    for (int k=0;k<4;++k){ i0[k] = 1.0f/s0[k]; i1[k] = 1.0f/s1[k]; }
    if (va){
      *reinterpret_cast<f32x4*>(coef + (size_t)pa*8)     = pa0 * i0 * ea0;
      *reinterpret_cast<f32x4*>(coef + (size_t)pa*8 + 4) = pa1 * i1 * ea1;
    }
    if (vb){
      *reinterpret_cast<f32x4*>(coef + (size_t)pb*8)     = pb0 * i0 * eb0;
      *reinterpret_cast<f32x4*>(coef + (size_t)pb*8 + 4) = pb1 * i1 * eb1;
    }
  } else {
    f32x4 m0 = (f32x4)(-3e38f), m1 = (f32x4)(-3e38f);
    for (int p = beg + l; p < end; p += 16){
      const int id = eid[p], s = srcc[p];
      const f32x4 e0v = *reinterpret_cast<const f32x4*>(ee + (size_t)id*8);
      const f32x4 e1v = *reinterpret_cast<const f32x4*>(ee + (size_t)id*8 + 4);
      const f32x4 l0 = *reinterpret_cast<const f32x4*>(el + (size_t)s*8);
      const f32x4 l1 = *reinterpret_cast<const f32x4*>(el + (size_t)s*8 + 4);
      m0 = max4(m0, leaky4(e0v + l0 + er0));
      m1 = max4(m1, leaky4(e1v + l1 + er1));
    }
#pragma unroll
    for (int m=1;m<16;m<<=1){
#pragma unroll
      for (int k=0;k<4;++k){
        m0[k] = fmaxf(m0[k], __shfl_xor(m0[k], m, 64));
        m1[k] = fmaxf(m1[k], __shfl_xor(m1[k], m, 64));
      }
    }
    f32x4 s0 = (f32x4)0.0f, s1 = (f32x4)0.0f;
    for (int p = beg + l; p < end; p += 16){
      const int id = eid[p], s = srcc[p];
      const f32x4 e0v = *reinterpret_cast<const f32x4*>(ee + (size_t)id*8);
      const f32x4 e1v = *reinterpret_cast<const f32x4*>(ee + (size_t)id*8 + 4);
      const f32x4 l0 = *reinterpret_cast<const f32x4*>(el + (size_t)s*8);
      const f32x4 l1 = *reinterpret_cast<const f32x4*>(el + (size_t)s*8 + 4);
      s0 += exp4(leaky4(e0v + l0 + er0) - m0);
      s1 += exp4(leaky4(e1v + l1 + er1) - m1);
    }
#pragma unroll
    for (int m=1;m<16;m<<=1){
#pragma unroll
      for (int k=0;k<4;++k){
        s0[k] += __shfl_xor(s0[k], m, 64);
        s1[k] += __shfl_xor(s1[k], m, 64);
      }
    }
    f32x4 i0, i1;
#pragma unroll
    for (int k=0;k<4;++k){ i0[k] = 1.0f/s0[k]; i1[k] = 1.0f/s1[k]; }
    for (int p = beg + l; p < end; p += 16){
      const int id = eid[p], s = srcc[p];
      const f32x4 e0v = *reinterpret_cast<const f32x4*>(ee + (size_t)id*8);
      const f32x4 e1v = *reinterpret_cast<const f32x4*>(ee + (size_t)id*8 + 4);
      const f32x4 l0 = *reinterpret_cast<const f32x4*>(el + (size_t)s*8);
      const f32x4 l1 = *reinterpret_cast<const f32x4*>(el + (size_t)s*8 + 4);
      const f32x4 o0 = exp4(leaky4(e0v + l0 + er0) - m0) * i0 * e0v;
      const f32x4 o1 = exp4(leaky4(e1v + l1 + er1) - m1) * i1 * e1v;
      *reinterpret_cast<f32x4*>(coef + (size_t)p*8) = o0;
      *reinterpret_cast<f32x4*>(coef + (size_t)p*8 + 4) = o1;
    }
  }
}

// ---------- aggregation: block per node, 4 waves x 2 edges each in flight ----------
__global__ __launch_bounds__(256) void k_agg(
    const int* __restrict__ rowptr, const int* __restrict__ srcc,
    const float* __restrict__ coef, const short* __restrict__ featb,
    const float* __restrict__ bias, float* __restrict__ out)
{
  __shared__ float red[4][32][8];
  const int n = blockIdx.x;
  const int t = threadIdx.x, l = t & 63, w = t >> 6;
  const int half = l >> 5, cl = l & 31;      // channels cl*8..cl*8+7
  const int h = cl >> 2;                      // head for these channels
  const int beg = rowptr[n], end = rowptr[n+1];
  float acc[8];
#pragma unroll
  for (int k=0;k<8;++k) acc[k] = 0.f;
  for (int p = beg + w*2 + half; p < end; p += 8){
    const int s = srcc[p];
    const float cf = coef[(size_t)p*8 + h];
    const short8v fv = *reinterpret_cast<const short8v*>(featb + (size_t)s*HD + cl*8);
#pragma unroll
    for (int k=0;k<8;++k) acc[k] += cf * b2f(fv[k]);
  }
#pragma unroll
  for (int k=0;k<8;++k) acc[k] += __shfl_xor(acc[k], 32, 64);
  if (half == 0){
#pragma unroll
    for (int k=0;k<8;++k) red[w][cl][k] = acc[k];
  }
  __syncthreads();
  {
    const int cl2 = t >> 3, k2 = t & 7;
    out[(size_t)n*HD + t] = red[0][cl2][k2] + red[1][cl2][k2] + red[2][cl2][k2]
                          + red[3][cl2][k2] + bias[t];
  }
}

extern "C" void kernel_launch(void* const* d_in, const int* in_sizes, int n_in,
                              void* d_out, int out_size, void* d_ws, size_t ws_size,
                              hipStream_t stream) {
  const float* nfeat  = (const float*)d_in[0];
  const float* efeat  = (const float*)d_in[1];
  const float* rij    = (const float*)d_in[2];
  const int*   src    = (const int*)d_in[3];
  const int*   dst    = (const int*)d_in[4];
  const float* W_fc   = (const float*)d_in[5];
  const float* W_e1   = (const float*)d_in[6];
  const float* b_e1   = (const float*)d_in[7];
  const float* W_e2   = (const float*)d_in[8];
  const float* b_e2   = (const float*)d_in[9];
  const float* attn_l = (const float*)d_in[10];
  const float* attn_r = (const float*)d_in[11];
  const float* attn_e = (const float*)d_in[12];
  const float* bias   = (const float*)d_in[13];
  float* out = (float*)d_out;

  size_t off = 0;
  auto carve = [&](size_t nbytes) -> void* {
    void* p = (char*)d_ws + off;
    off += (nbytes + 255) & ~(size_t)255;
    return p;
  };
  short* featb = (short*)carve((size_t)NN*HD*2);
  float* el    = (float*)carve((size_t)NN*8*4);
  float* er    = (float*)carve((size_t)NN*8*4);
  float* ee    = (float*)carve((size_t)NE*8*4);
  float* coef  = (float*)carve((size_t)NE*8*4);
  int* deg     = (int*)carve((size_t)NN*4);
  int* rowptr  = (int*)carve((size_t)(NN+1)*4);
  int* fillptr = (int*)carve((size_t)(NN+1)*4);
  int* eidb    = (int*)carve((size_t)NE*4);
  int* srcc    = (int*)carve((size_t)NE*4);
  int* bsum    = (int*)carve((size_t)SCAN_B*4);
  int* boff    = (int*)carve((size_t)SCAN_B*4);
  int* total   = (int*)carve(4);
  short* wfcb  = (short*)carve((size_t)HD*KIN*2);
  short* we1b  = (short*)carve((size_t)32*KIN*2);
  short* we2b  = (short*)carve((size_t)HD*32*2);

  hipMemsetAsync(deg, 0, (size_t)NN*4, stream);
  k_convert<<<128, 256, 0, stream>>>(W_fc, W_e1, W_e2, wfcb, we1b, we2b);
  k_feat<<<(NN+63)/64, 256, 0, stream>>>(nfeat, wfcb, attn_l, attn_r, featb, el, er);
  k_hist<<<1024, 256, 0, stream>>>(dst, deg);
  k_scanA<<<SCAN_B, 1024, 0, stream>>>(deg, bsum);
  k_scanB<<<1, 64, 0, stream>>>(bsum, boff, total);
  k_scanC<<<SCAN_B, 1024, 0, stream>>>(deg, boff, total, rowptr, fillptr);
  k_fill<<<1024, 256, 0, stream>>>(dst, src, fillptr, eidb, srcc);
  k_edge<<<NE/64, 256, 0, stream>>>(efeat, rij, we1b, b_e1, we2b, b_e2, attn_e, ee);
  k_softmax<<<(NN+15)/16, 256, 0, stream>>>(rowptr, eidb, srcc, el, er, ee, coef);
  k_agg<<<NN, 256, 0, stream>>>(rowptr, srcc, coef, featb, bias, out);
}

// Round 8
// 444.811 us; speedup vs baseline: 1.4749x; 1.0082x over previous
//
#include <hip/hip_runtime.h>
#include <hip/hip_bf16.h>

#define NN 50000
#define NE 800000
#define HD 256
#define KIN 128
#define SCAN_B 49

typedef __attribute__((ext_vector_type(8))) short bf16x8;
typedef __attribute__((ext_vector_type(8))) short short8v;
typedef __attribute__((ext_vector_type(4))) float f32x4;

static __device__ __forceinline__ short f2b(float f){
  union { __hip_bfloat16 h; short s; } u;
  u.h = __float2bfloat16(f);
  return u.s;
}
static __device__ __forceinline__ float b2f(short s){
  union { __hip_bfloat16 h; short s; } u;
  u.s = s;
  return __bfloat162float(u.h);
}
static __device__ __forceinline__ unsigned packbf(float a, float b){
  union { short s[2]; unsigned u; } z;
  z.s[0] = f2b(a); z.s[1] = f2b(b);
  return z.u;
}
// softplus(x)-log(2) on raw v_exp/v_log (2^x / log2): saves the scale muls
static __device__ __forceinline__ float sspf(float x){
#if __has_builtin(__builtin_amdgcn_exp2f) && __has_builtin(__builtin_amdgcn_logf)
  const float t = __builtin_amdgcn_exp2f(fabsf(x) * -1.4426950408889634f);
  return fmaf(__builtin_amdgcn_logf(1.0f + t) - 1.0f, 0.69314718055994531f, fmaxf(x, 0.0f));
#else
  const float t = __expf(-fabsf(x));
  return fmaxf(x, 0.0f) + __logf(1.0f + t) - 0.69314718055994531f;
#endif
}
static __device__ __forceinline__ f32x4 leaky4(f32x4 x){
  f32x4 r;
#pragma unroll
  for (int k=0;k<4;++k) r[k] = x[k] > 0.f ? x[k] : 0.2f*x[k];
  return r;
}
static __device__ __forceinline__ f32x4 max4(f32x4 a, f32x4 b){
  f32x4 r;
#pragma unroll
  for (int k=0;k<4;++k) r[k] = fmaxf(a[k], b[k]);
  return r;
}
static __device__ __forceinline__ f32x4 exp4(f32x4 x){
  f32x4 r;
#pragma unroll
  for (int k=0;k<4;++k) r[k] = __expf(x[k]);
  return r;
}

// ---------- weight fp32 -> bf16 (+ packed be2/attn_e epilogue table) ----------
__global__ void k_convert(const float* __restrict__ wfc, const float* __restrict__ we1,
                          const float* __restrict__ we2,
                          const float* __restrict__ be2, const float* __restrict__ attn_e,
                          short* __restrict__ wfcb, short* __restrict__ we1b,
                          short* __restrict__ we2b, float* __restrict__ w2pk){
  const int i = blockIdx.x*256 + threadIdx.x;
  if (i < HD*KIN) wfcb[i] = f2b(wfc[i]);
  if (i < 32*KIN) we1b[i] = f2b(we1[i]);
  if (i < HD*32)  we2b[i] = f2b(we2[i]);
  if (i < 512){
    // w2pk[cht*32 + lq*8 + j]: j<4 -> be2[cht*16+lq*4+j], j>=4 -> attn_e[...]
    const int cht = i >> 5, r = i & 31, lq = r >> 3, j = r & 7;
    const int ch = cht*16 + lq*4 + (j & 3);
    w2pk[i] = (j < 4) ? be2[ch] : attn_e[ch];
  }
}

// ---------- feat = nfeat @ W_fc^T  (+ el, er) ----------
__global__ __launch_bounds__(256) void k_feat(
    const float* __restrict__ nfeat, const short* __restrict__ wfcb,
    const float* __restrict__ attn_l, const float* __restrict__ attn_r,
    short* __restrict__ featb, float* __restrict__ el, float* __restrict__ er)
{
  const int n0 = blockIdx.x * 64;
  const int tid = threadIdx.x;
  const int w = tid >> 6, l = tid & 63, l15 = l & 15, lq = l >> 4;

  f32x4 acc[4][4];
#pragma unroll
  for (int a=0;a<4;++a)
#pragma unroll
    for (int b=0;b<4;++b) acc[a][b] = (f32x4)0.0f;

#pragma unroll
  for (int ks=0; ks<4; ++ks){
    const int k0 = ks*32 + lq*8;
    bf16x8 af[4];
#pragma unroll
    for (int tr=0; tr<4; ++tr){
      int row = n0 + tr*16 + l15;
      if (row >= NN) row = NN-1;
      const float4 x0 = *reinterpret_cast<const float4*>(nfeat + (size_t)row*KIN + k0);
      const float4 x1 = *reinterpret_cast<const float4*>(nfeat + (size_t)row*KIN + k0 + 4);
      af[tr][0]=f2b(x0.x); af[tr][1]=f2b(x0.y); af[tr][2]=f2b(x0.z); af[tr][3]=f2b(x0.w);
      af[tr][4]=f2b(x1.x); af[tr][5]=f2b(x1.y); af[tr][6]=f2b(x1.z); af[tr][7]=f2b(x1.w);
    }
#pragma unroll
    for (int tc=0; tc<4; ++tc){
      const int c = w*64 + tc*16 + l15;
      const bf16x8 bfrag = *reinterpret_cast<const bf16x8*>(wfcb + c*KIN + k0);
#pragma unroll
      for (int tr=0; tr<4; ++tr)
        acc[tr][tc] = __builtin_amdgcn_mfma_f32_16x16x32_bf16(af[tr], bfrag, acc[tr][tc], 0,0,0);
    }
  }

  float alr[4], arr_[4];
#pragma unroll
  for (int tc=0;tc<4;++tc){
    const int c = w*64 + tc*16 + l15;
    alr[tc] = attn_l[c]; arr_[tc] = attn_r[c];
  }
  float pl[4][4][2], pr[4][4][2];
#pragma unroll
  for (int tr=0;tr<4;++tr)
#pragma unroll
    for (int j=0;j<4;++j){ pl[tr][j][0]=pl[tr][j][1]=0.f; pr[tr][j][0]=pr[tr][j][1]=0.f; }

#pragma unroll
  for (int tr=0;tr<4;++tr){
    const int rowb = tr*16 + lq*4;
#pragma unroll
    for (int tc=0;tc<4;++tc){
      const int c = w*64 + tc*16 + l15;
      const int h2 = tc>>1;
#pragma unroll
      for (int j=0;j<4;++j){
        const float v = acc[tr][tc][j];
        const int node = n0 + rowb + j;
        if (node < NN) featb[node*HD + c] = f2b(v);
        pl[tr][j][h2] += v*alr[tc];
        pr[tr][j][h2] += v*arr_[tc];
      }
    }
  }
#pragma unroll
  for (int m=1;m<16;m<<=1){
#pragma unroll
    for (int tr=0;tr<4;++tr)
#pragma unroll
      for (int j=0;j<4;++j){
        pl[tr][j][0] += __shfl_xor(pl[tr][j][0], m, 64);
        pl[tr][j][1] += __shfl_xor(pl[tr][j][1], m, 64);
        pr[tr][j][0] += __shfl_xor(pr[tr][j][0], m, 64);
        pr[tr][j][1] += __shfl_xor(pr[tr][j][1], m, 64);
      }
  }
#pragma unroll
  for (int tr=0;tr<4;++tr)
#pragma unroll
    for (int j=0;j<4;++j)
      if (l15 == tr*4+j){
        const int node = n0 + tr*16 + lq*4 + j;
        if (node < NN){
          el[node*8 + 2*w + 0] = pl[tr][j][0];
          el[node*8 + 2*w + 1] = pl[tr][j][1];
          er[node*8 + 2*w + 0] = pr[tr][j][0];
          er[node*8 + 2*w + 1] = pr[tr][j][1];
        }
      }
}

// ---------- CSR build ----------
__global__ void k_hist(const int* __restrict__ dst, int* __restrict__ deg){
  for (int i = blockIdx.x*blockDim.x + threadIdx.x; i < NE; i += gridDim.x*blockDim.x)
    atomicAdd(&deg[dst[i]], 1);
}

__global__ __launch_bounds__(1024) void k_scanA(const int* __restrict__ deg,
                                                int* __restrict__ bsum){
  __shared__ int ws[16];
  const int t = threadIdx.x;
  const int i = blockIdx.x*1024 + t;
  int v = (i < NN) ? deg[i] : 0;
#pragma unroll
  for (int m=1;m<64;m<<=1) v += __shfl_xor(v, m, 64);
  if ((t & 63) == 0) ws[t >> 6] = v;
  __syncthreads();
  if (t == 0){
    int s = 0;
#pragma unroll
    for (int k=0;k<16;++k) s += ws[k];
    bsum[blockIdx.x] = s;
  }
}
__global__ void k_scanB(const int* __restrict__ bsum, int* __restrict__ boff,
                        int* __restrict__ total){
  const int t = threadIdx.x;  // 64 threads
  const int v = (t < SCAN_B) ? bsum[t] : 0;
  int x = v;
#pragma unroll
  for (int off=1; off<64; off<<=1){
    const int y = __shfl_up(x, off, 64);
    if (t >= off) x += y;
  }
  if (t < SCAN_B) boff[t] = x - v;
  if (t == 63) *total = x;
}
__global__ __launch_bounds__(1024) void k_scanC(const int* __restrict__ deg,
                                                const int* __restrict__ boff,
                                                const int* __restrict__ total,
                                                int* __restrict__ rowptr,
                                                int* __restrict__ fillptr){
  __shared__ int ws[16];
  const int t = threadIdx.x, l = t & 63, wid = t >> 6;
  const int i = blockIdx.x*1024 + t;
  const int v = (i < NN) ? deg[i] : 0;
  int x = v;
#pragma unroll
  for (int off=1; off<64; off<<=1){
    const int y = __shfl_up(x, off, 64);
    if (l >= off) x += y;
  }
  if (l == 63) ws[wid] = x;
  __syncthreads();
  if (t == 0){
    int run = 0;
#pragma unroll
    for (int k=0;k<16;++k){ const int tmp = ws[k]; ws[k] = run; run += tmp; }
  }
  __syncthreads();
  if (i < NN){
    const int excl = boff[blockIdx.x] + ws[wid] + (x - v);
    rowptr[i] = excl; fillptr[i] = excl;
  }
  if (blockIdx.x == 0 && t == 0) rowptr[NN] = *total;
}

__global__ void k_fill(const int* __restrict__ dst, const int* __restrict__ src,
                       int* __restrict__ fillptr,
                       int* __restrict__ eid, int* __restrict__ srcc){
  for (int i = blockIdx.x*blockDim.x + threadIdx.x; i < NE; i += gridDim.x*blockDim.x){
    const int p = atomicAdd(&fillptr[dst[i]], 1);
    eid[p] = i;
    srcc[p] = src[i];
  }
}

// ---------- fused edge MLP -> ee: wave-independent, zero LDS/barriers ----------
__global__ __launch_bounds__(256, 4) void k_edge(
    const float* __restrict__ efeat, const float* __restrict__ rij,
    const short* __restrict__ we1b, const float* __restrict__ be1,
    const short* __restrict__ we2b, const float* __restrict__ w2pk,
    float* __restrict__ ee)
{
  const int tid = threadIdx.x;
  const int w = tid >> 6, l = tid & 63, l15 = l & 15, lq = l >> 4;
  const int e0w = blockIdx.x * 64 + w * 16;   // this wave's 16 edges

  // hoist all 8 efeat float4 loads (8 outstanding vmem)
  const float* erow = efeat + (size_t)(e0w + l15)*KIN + lq*8;
  const float4 r0 = *reinterpret_cast<const float4*>(erow);
  const float4 r1 = *reinterpret_cast<const float4*>(erow + 4);
  const float4 r2 = *reinterpret_cast<const float4*>(erow + 32);
  const float4 r3 = *reinterpret_cast<const float4*>(erow + 36);
  const float4 r4 = *reinterpret_cast<const float4*>(erow + 64);
  const float4 r5 = *reinterpret_cast<const float4*>(erow + 68);
  const float4 r6 = *reinterpret_cast<const float4*>(erow + 96);
  const float4 r7 = *reinterpret_cast<const float4*>(erow + 100);
  const float rv = rij[e0w + l15];

  // GEMM1 swapped: D_th[row=hidden th*16+lq*4+j][col=edge l15]
  f32x4 acc_t0 = (f32x4)0.0f, acc_t1 = (f32x4)0.0f;
  float4 raw[8] = {r0,r1,r2,r3,r4,r5,r6,r7};
#pragma unroll
  for (int ks=0; ks<4; ++ks){
    const int k0 = ks*32 + lq*8;
    bf16x8 bfr;
    bfr[0]=f2b(raw[2*ks].x); bfr[1]=f2b(raw[2*ks].y); bfr[2]=f2b(raw[2*ks].z); bfr[3]=f2b(raw[2*ks].w);
    bfr[4]=f2b(raw[2*ks+1].x); bfr[5]=f2b(raw[2*ks+1].y); bfr[6]=f2b(raw[2*ks+1].z); bfr[7]=f2b(raw[2*ks+1].w);
    const bf16x8 a0 = *reinterpret_cast<const bf16x8*>(we1b + (l15     )*KIN + k0);
    const bf16x8 a1 = *reinterpret_cast<const bf16x8*>(we1b + (16 + l15)*KIN + k0);
    acc_t0 = __builtin_amdgcn_mfma_f32_16x16x32_bf16(a0, bfr, acc_t0, 0,0,0);
    acc_t1 = __builtin_amdgcn_mfma_f32_16x16x32_bf16(a1, bfr, acc_t1, 0,0,0);
  }

  // bias + ssp; lane holds X[edge l15][hidden lq*4+j] (th0) and [16+lq*4+j] (th1)
  const f32x4 b1a = *reinterpret_cast<const f32x4*>(be1 + lq*4);
  const f32x4 b1b = *reinterpret_cast<const f32x4*>(be1 + 16 + lq*4);
  const unsigned t0lo = packbf(sspf(acc_t0[0]+b1a[0]), sspf(acc_t0[1]+b1a[1]));
  const unsigned t0hi = packbf(sspf(acc_t0[2]+b1a[2]), sspf(acc_t0[3]+b1a[3]));
  const unsigned t1lo = packbf(sspf(acc_t1[0]+b1b[0]), sspf(acc_t1[1]+b1b[1]));
  const unsigned t1hi = packbf(sspf(acc_t1[2]+b1b[2]), sspf(acc_t1[3]+b1b[3]));

  // permute to GEMM2 B-frag: lane needs X[edge l15][hidden lq*8 .. lq*8+7]
  const int srcA = ((lq & 1) << 5) + l15;
  const int srcB = srcA + 16;
  const int a_lo0 = __shfl((int)t0lo, srcA, 64), a_hi0 = __shfl((int)t0hi, srcA, 64);
  const int b_lo0 = __shfl((int)t0lo, srcB, 64), b_hi0 = __shfl((int)t0hi, srcB, 64);
  const int a_lo1 = __shfl((int)t1lo, srcA, 64), a_hi1 = __shfl((int)t1hi, srcA, 64);
  const int b_lo1 = __shfl((int)t1lo, srcB, 64), b_hi1 = __shfl((int)t1hi, srcB, 64);
  const bool th1sel = (lq & 2);
  union { int u[4]; bf16x8 v; } bx;
  bx.u[0] = th1sel ? a_lo1 : a_lo0;
  bx.u[1] = th1sel ? a_hi1 : a_hi0;
  bx.u[2] = th1sel ? b_lo1 : b_lo0;
  bx.u[3] = th1sel ? b_hi1 : b_hi0;

  // GEMM2: 16 channel tiles; per cht only 2 loads (a2 + packed {be2,attn_e})
  const float* pkb = w2pk + lq*8;
  float pe[8];
#pragma unroll
  for (int h=0;h<8;++h) pe[h] = 0.f;
#pragma unroll
  for (int cht=0; cht<16; ++cht){
    const bf16x8 a2 = *reinterpret_cast<const bf16x8*>(we2b + (cht*16 + l15)*32 + lq*8);
    const f32x4 d = __builtin_amdgcn_mfma_f32_16x16x32_bf16(a2, bx.v, (f32x4)0.0f, 0,0,0);
    const f32x4 b2v = *reinterpret_cast<const f32x4*>(pkb + cht*32);
    const f32x4 aev = *reinterpret_cast<const f32x4*>(pkb + cht*32 + 4);
    float s = 0.f;
#pragma unroll
    for (int j=0;j<4;++j) s = fmaf(sspf(d[j] + b2v[j]), aev[j], s);
    pe[cht>>1] += s;
  }
#pragma unroll
  for (int h=0;h<8;++h){
    pe[h] += __shfl_xor(pe[h], 16, 64);
    pe[h] += __shfl_xor(pe[h], 32, 64);
  }
  const float fcv = (rv < 5.0f) ? 0.5f*(__cosf(0.62831853071795864f*rv) + 1.0f) : 0.0f;
  const float o0 = (lq==0) ? pe[0] : (lq==1) ? pe[2] : (lq==2) ? pe[4] : pe[6];
  const float o1 = (lq==0) ? pe[1] : (lq==1) ? pe[3] : (lq==2) ? pe[5] : pe[7];
  float2 outv; outv.x = o0*fcv; outv.y = o1*fcv;
  *reinterpret_cast<float2*>(ee + (size_t)(e0w + l15)*8 + lq*2) = outv;
}

// ---------- fused softmax + aggregation: block per node, 256-thread softmax ----------
__global__ __launch_bounds__(256) void k_sa(
    const int* __restrict__ rowptr, const int* __restrict__ eid,
    const int* __restrict__ srcc,
    const float* __restrict__ el, const float* __restrict__ er,
    const float* __restrict__ ee, const short* __restrict__ featb,
    const float* __restrict__ bias, float* __restrict__ coefg,
    float* __restrict__ out)
{
  __shared__ float cf[32][8];
  __shared__ float mx[4][8], sm[4][8];
  __shared__ float red[4][32][8];
  const int n = blockIdx.x;
  const int t = threadIdx.x, l = t & 63, w = t >> 6;
  const int beg = rowptr[n], end = rowptr[n+1];
  const int deg = end - beg;

  if (deg <= 32){
    // 32 slots x 8 heads; thread t -> slot t>>3, head t&7
    const int slot = t >> 3, h = t & 7;
    const int p = beg + slot;
    const bool valid = p < end;
    float x = 0.f, e = -3e38f;
    if (valid){
      const int id = eid[p], sc = srcc[p];
      x = ee[(size_t)id*8 + h];
      e = x + el[(size_t)sc*8 + h] + er[(size_t)n*8 + h];
      e = e > 0.f ? e : 0.2f*e;
    }
    float m = e;
    m = fmaxf(m, __shfl_xor(m, 8, 64));
    m = fmaxf(m, __shfl_xor(m, 16, 64));
    m = fmaxf(m, __shfl_xor(m, 32, 64));
    if (l < 8) mx[w][l] = m;
    __syncthreads();
    m = fmaxf(fmaxf(mx[0][h], mx[1][h]), fmaxf(mx[2][h], mx[3][h]));
    const float pexp = valid ? __expf(e - m) : 0.f;
    float s = pexp;
    s += __shfl_xor(s, 8, 64);
    s += __shfl_xor(s, 16, 64);
    s += __shfl_xor(s, 32, 64);
    if (l < 8) sm[w][l] = s;
    __syncthreads();
    s = sm[0][h] + sm[1][h] + sm[2][h] + sm[3][h];
    if (valid) cf[slot][h] = pexp / s * x;
  } else {
    // rare fallback: 3-pass with 64 threads into coefg
    if (t < 64){
      const f32x4 er0 = *reinterpret_cast<const f32x4*>(er + (size_t)n*8);
      const f32x4 er1 = *reinterpret_cast<const f32x4*>(er + (size_t)n*8 + 4);
      f32x4 m0 = (f32x4)(-3e38f), m1 = (f32x4)(-3e38f);
      for (int p = beg + t; p < end; p += 64){
        const int id = eid[p], s2 = srcc[p];
        const f32x4 e0v = *reinterpret_cast<const f32x4*>(ee + (size_t)id*8);
        const f32x4 e1v = *reinterpret_cast<const f32x4*>(ee + (size_t)id*8 + 4);
        const f32x4 l0 = *reinterpret_cast<const f32x4*>(el + (size_t)s2*8);
        const f32x4 l1 = *reinterpret_cast<const f32x4*>(el + (size_t)s2*8 + 4);
        m0 = max4(m0, leaky4(e0v + l0 + er0));
        m1 = max4(m1, leaky4(e1v + l1 + er1));
      }
#pragma unroll
      for (int m=1;m<64;m<<=1){
#pragma unroll
        for (int k=0;k<4;++k){
          m0[k] = fmaxf(m0[k], __shfl_xor(m0[k], m, 64));
          m1[k] = fmaxf(m1[k], __shfl_xor(m1[k], m, 64));
        }
      }
      f32x4 s0 = (f32x4)0.0f, s1 = (f32x4)0.0f;
      for (int p = beg + t; p < end; p += 64){
        const int id = eid[p], s2 = srcc[p];
        const f32x4 e0v = *reinterpret_cast<const f32x4*>(ee + (size_t)id*8);
        const f32x4 e1v = *reinterpret_cast<const f32x4*>(ee + (size_t)id*8 + 4);
        const f32x4 l0 = *reinterpret_cast<const f32x4*>(el + (size_t)s2*8);
        const f32x4 l1 = *reinterpret_cast<const f32x4*>(el + (size_t)s2*8 + 4);
        s0 += exp4(leaky4(e0v + l0 + er0) - m0);
        s1 += exp4(leaky4(e1v + l1 + er1) - m1);
      }
#pragma unroll
      for (int m=1;m<64;m<<=1){
#pragma unroll
        for (int k=0;k<4;++k){
          s0[k] += __shfl_xor(s0[k], m, 64);
          s1[k] += __shfl_xor(s1[k], m, 64);
        }
      }
      f32x4 i0, i1;
#pragma unroll
      for (int k=0;k<4;++k){ i0[k] = 1.0f/s0[k]; i1[k] = 1.0f/s1[k]; }
      for (int p = beg + t; p < end; p += 64){
        const int id = eid[p], s2 = srcc[p];
        const f32x4 e0v = *reinterpret_cast<const f32x4*>(ee + (size_t)id*8);
        const f32x4 e1v = *reinterpret_cast<const f32x4*>(ee + (size_t)id*8 + 4);
        const f32x4 l0 = *reinterpret_cast<const f32x4*>(el + (size_t)s2*8);
        const f32x4 l1 = *reinterpret_cast<const f32x4*>(el + (size_t)s2*8 + 4);
        const f32x4 o0 = exp4(leaky4(e0v + l0 + er0) - m0) * i0 * e0v;
        const f32x4 o1 = exp4(leaky4(e1v + l1 + er1) - m1) * i1 * e1v;
        *reinterpret_cast<f32x4*>(coefg + (size_t)p*8) = o0;
        *reinterpret_cast<f32x4*>(coefg + (size_t)p*8 + 4) = o1;
      }
    }
  }
  __syncthreads();

  // aggregation: 4 waves x 2 halves = 8 edges in flight
  const int half = l >> 5, cl = l & 31;
  const int hh = cl >> 2;
  const bool inlds = (deg <= 32);
  float acc[8];
#pragma unroll
  for (int k=0;k<8;++k) acc[k] = 0.f;
  for (int p = beg + w*2 + half; p < end; p += 8){
    const int s = srcc[p];
    const float c = inlds ? cf[p-beg][hh] : coefg[(size_t)p*8 + hh];
    const short8v fv = *reinterpret_cast<const short8v*>(featb + (size_t)s*HD + cl*8);
#pragma unroll
    for (int k=0;k<8;++k) acc[k] = fmaf(c, b2f(fv[k]), acc[k]);
  }
#pragma unroll
  for (int k=0;k<8;++k) acc[k] += __shfl_xor(acc[k], 32, 64);
  if (half == 0){
#pragma unroll
    for (int k=0;k<8;++k) red[w][cl][k] = acc[k];
  }
  __syncthreads();
  {
    const int cl2 = t >> 3, k2 = t & 7;
    out[(size_t)n*HD + t] = red[0][cl2][k2] + red[1][cl2][k2] + red[2][cl2][k2]
                          + red[3][cl2][k2] + bias[t];
  }
}

extern "C" void kernel_launch(void* const* d_in, const int* in_sizes, int n_in,
                              void* d_out, int out_size, void* d_ws, size_t ws_size,
                              hipStream_t stream) {
  const float* nfeat  = (const float*)d_in[0];
  const float* efeat  = (const float*)d_in[1];
  const float* rij    = (const float*)d_in[2];
  const int*   src    = (const int*)d_in[3];
  const int*   dst    = (const int*)d_in[4];
  const float* W_fc   = (const float*)d_in[5];
  const float* W_e1   = (const float*)d_in[6];
  const float* b_e1   = (const float*)d_in[7];
  const float* W_e2   = (const float*)d_in[8];
  const float* b_e2   = (const float*)d_in[9];
  const float* attn_l = (const float*)d_in[10];
  const float* attn_r = (const float*)d_in[11];
  const float* attn_e = (const float*)d_in[12];
  const float* bias   = (const float*)d_in[13];
  float* out = (float*)d_out;

  size_t off = 0;
  auto carve = [&](size_t nbytes) -> void* {
    void* p = (char*)d_ws + off;
    off += (nbytes + 255) & ~(size_t)255;
    return p;
  };
  short* featb = (short*)carve((size_t)NN*HD*2);
  float* el    = (float*)carve((size_t)NN*8*4);
  float* er    = (float*)carve((size_t)NN*8*4);
  float* ee    = (float*)carve((size_t)NE*8*4);
  float* coefg = (float*)carve((size_t)NE*8*4);
  int* deg     = (int*)carve((size_t)NN*4);
  int* rowptr  = (int*)carve((size_t)(NN+1)*4);
  int* fillptr = (int*)carve((size_t)(NN+1)*4);
  int* eidb    = (int*)carve((size_t)NE*4);
  int* srcc    = (int*)carve((size_t)NE*4);
  int* bsum    = (int*)carve((size_t)SCAN_B*4);
  int* boff    = (int*)carve((size_t)SCAN_B*4);
  int* total   = (int*)carve(4);
  short* wfcb  = (short*)carve((size_t)HD*KIN*2);
  short* we1b  = (short*)carve((size_t)32*KIN*2);
  short* we2b  = (short*)carve((size_t)HD*32*2);
  float* w2pk  = (float*)carve((size_t)512*4);

  hipMemsetAsync(deg, 0, (size_t)NN*4, stream);
  k_convert<<<128, 256, 0, stream>>>(W_fc, W_e1, W_e2, b_e2, attn_e, wfcb, we1b, we2b, w2pk);
  k_feat<<<(NN+63)/64, 256, 0, stream>>>(nfeat, wfcb, attn_l, attn_r, featb, el, er);
  k_hist<<<1024, 256, 0, stream>>>(dst, deg);
  k_scanA<<<SCAN_B, 1024, 0, stream>>>(deg, bsum);
  k_scanB<<<1, 64, 0, stream>>>(bsum, boff, total);
  k_scanC<<<SCAN_B, 1024, 0, stream>>>(deg, boff, total, rowptr, fillptr);
  k_fill<<<1024, 256, 0, stream>>>(dst, src, fillptr, eidb, srcc);
  k_edge<<<NE/64, 256, 0, stream>>>(efeat, rij, we1b, b_e1, we2b, w2pk, ee);
  k_sa<<<NN, 256, 0, stream>>>(rowptr, eidb, srcc, el, er, ee, featb, bias, coefg, out);
}

// Round 9
// 441.386 us; speedup vs baseline: 1.4863x; 1.0078x over previous
//
#include <hip/hip_runtime.h>
#include <hip/hip_bf16.h>

#define NN 50000
#define NE 800000
#define HD 256
#define KIN 128
#define SCAN_B 49

typedef __attribute__((ext_vector_type(8))) short bf16x8;
typedef __attribute__((ext_vector_type(8))) short short8v;
typedef __attribute__((ext_vector_type(4))) float f32x4;

static __device__ __forceinline__ short f2b(float f){
  union { __hip_bfloat16 h; short s; } u;
  u.h = __float2bfloat16(f);
  return u.s;
}
static __device__ __forceinline__ float b2f(short s){
  union { __hip_bfloat16 h; short s; } u;
  u.s = s;
  return __bfloat162float(u.h);
}
static __device__ __forceinline__ unsigned packbf(float a, float b){
  union { short s[2]; unsigned u; } z;
  z.s[0] = f2b(a); z.s[1] = f2b(b);
  return z.u;
}
// softplus(x)-log(2) on raw v_exp/v_log
static __device__ __forceinline__ float sspf(float x){
#if __has_builtin(__builtin_amdgcn_exp2f) && __has_builtin(__builtin_amdgcn_logf)
  const float t = __builtin_amdgcn_exp2f(fabsf(x) * -1.4426950408889634f);
  return fmaf(__builtin_amdgcn_logf(1.0f + t) - 1.0f, 0.69314718055994531f, fmaxf(x, 0.0f));
#else
  const float t = __expf(-fabsf(x));
  return fmaxf(x, 0.0f) + __logf(1.0f + t) - 0.69314718055994531f;
#endif
}

// ---------- weight fp32 -> bf16 + packed epilogue table + degree histogram ----------
__global__ void k_cvh(const float* __restrict__ wfc, const float* __restrict__ we1,
                      const float* __restrict__ we2,
                      const float* __restrict__ be2, const float* __restrict__ attn_e,
                      const int* __restrict__ dst,
                      short* __restrict__ wfcb, short* __restrict__ we1b,
                      short* __restrict__ we2b, float* __restrict__ w2pk,
                      int* __restrict__ deg){
  const int i = blockIdx.x*256 + threadIdx.x;
  if (i < HD*KIN) wfcb[i] = f2b(wfc[i]);
  if (i < 32*KIN) we1b[i] = f2b(we1[i]);
  if (i < HD*32)  we2b[i] = f2b(we2[i]);
  if (i < 512){
    const int cht = i >> 5, r = i & 31, lq = r >> 3, j = r & 7;
    const int ch = cht*16 + lq*4 + (j & 3);
    w2pk[i] = (j < 4) ? be2[ch] : attn_e[ch];
  }
  for (int e = i; e < NE; e += gridDim.x*blockDim.x)
    atomicAdd(&deg[dst[e]], 1);
}

// ---------- feat = nfeat @ W_fc^T  (+ el, er) ----------
__global__ __launch_bounds__(256) void k_feat(
    const float* __restrict__ nfeat, const short* __restrict__ wfcb,
    const float* __restrict__ attn_l, const float* __restrict__ attn_r,
    short* __restrict__ featb, float* __restrict__ el, float* __restrict__ er)
{
  const int n0 = blockIdx.x * 64;
  const int tid = threadIdx.x;
  const int w = tid >> 6, l = tid & 63, l15 = l & 15, lq = l >> 4;

  f32x4 acc[4][4];
#pragma unroll
  for (int a=0;a<4;++a)
#pragma unroll
    for (int b=0;b<4;++b) acc[a][b] = (f32x4)0.0f;

#pragma unroll
  for (int ks=0; ks<4; ++ks){
    const int k0 = ks*32 + lq*8;
    bf16x8 af[4];
#pragma unroll
    for (int tr=0; tr<4; ++tr){
      int row = n0 + tr*16 + l15;
      if (row >= NN) row = NN-1;
      const float4 x0 = *reinterpret_cast<const float4*>(nfeat + (size_t)row*KIN + k0);
      const float4 x1 = *reinterpret_cast<const float4*>(nfeat + (size_t)row*KIN + k0 + 4);
      af[tr][0]=f2b(x0.x); af[tr][1]=f2b(x0.y); af[tr][2]=f2b(x0.z); af[tr][3]=f2b(x0.w);
      af[tr][4]=f2b(x1.x); af[tr][5]=f2b(x1.y); af[tr][6]=f2b(x1.z); af[tr][7]=f2b(x1.w);
    }
#pragma unroll
    for (int tc=0; tc<4; ++tc){
      const int c = w*64 + tc*16 + l15;
      const bf16x8 bfrag = *reinterpret_cast<const bf16x8*>(wfcb + c*KIN + k0);
#pragma unroll
      for (int tr=0; tr<4; ++tr)
        acc[tr][tc] = __builtin_amdgcn_mfma_f32_16x16x32_bf16(af[tr], bfrag, acc[tr][tc], 0,0,0);
    }
  }

  float alr[4], arr_[4];
#pragma unroll
  for (int tc=0;tc<4;++tc){
    const int c = w*64 + tc*16 + l15;
    alr[tc] = attn_l[c]; arr_[tc] = attn_r[c];
  }
  float pl[4][4][2], pr[4][4][2];
#pragma unroll
  for (int tr=0;tr<4;++tr)
#pragma unroll
    for (int j=0;j<4;++j){ pl[tr][j][0]=pl[tr][j][1]=0.f; pr[tr][j][0]=pr[tr][j][1]=0.f; }

#pragma unroll
  for (int tr=0;tr<4;++tr){
    const int rowb = tr*16 + lq*4;
#pragma unroll
    for (int tc=0;tc<4;++tc){
      const int c = w*64 + tc*16 + l15;
      const int h2 = tc>>1;
#pragma unroll
      for (int j=0;j<4;++j){
        const float v = acc[tr][tc][j];
        const int node = n0 + rowb + j;
        if (node < NN) featb[node*HD + c] = f2b(v);
        pl[tr][j][h2] += v*alr[tc];
        pr[tr][j][h2] += v*arr_[tc];
      }
    }
  }
#pragma unroll
  for (int m=1;m<16;m<<=1){
#pragma unroll
    for (int tr=0;tr<4;++tr)
#pragma unroll
      for (int j=0;j<4;++j){
        pl[tr][j][0] += __shfl_xor(pl[tr][j][0], m, 64);
        pl[tr][j][1] += __shfl_xor(pl[tr][j][1], m, 64);
        pr[tr][j][0] += __shfl_xor(pr[tr][j][0], m, 64);
        pr[tr][j][1] += __shfl_xor(pr[tr][j][1], m, 64);
      }
  }
#pragma unroll
  for (int tr=0;tr<4;++tr)
#pragma unroll
    for (int j=0;j<4;++j)
      if (l15 == tr*4+j){
        const int node = n0 + tr*16 + lq*4 + j;
        if (node < NN){
          el[node*8 + 2*w + 0] = pl[tr][j][0];
          el[node*8 + 2*w + 1] = pl[tr][j][1];
          er[node*8 + 2*w + 0] = pr[tr][j][0];
          er[node*8 + 2*w + 1] = pr[tr][j][1];
        }
      }
}

// ---------- CSR scan ----------
__global__ __launch_bounds__(1024) void k_scanA(const int* __restrict__ deg,
                                                int* __restrict__ bsum){
  __shared__ int ws[16];
  const int t = threadIdx.x;
  const int i = blockIdx.x*1024 + t;
  int v = (i < NN) ? deg[i] : 0;
#pragma unroll
  for (int m=1;m<64;m<<=1) v += __shfl_xor(v, m, 64);
  if ((t & 63) == 0) ws[t >> 6] = v;
  __syncthreads();
  if (t == 0){
    int s = 0;
#pragma unroll
    for (int k=0;k<16;++k) s += ws[k];
    bsum[blockIdx.x] = s;
  }
}

// scanC with fused block-offset scan (replaces scanB): wave0 scans the 49 block sums
__global__ __launch_bounds__(1024) void k_scanC(const int* __restrict__ deg,
                                                const int* __restrict__ bsum,
                                                int* __restrict__ rowptr,
                                                int* __restrict__ fillptr){
  __shared__ int ws[16];
  __shared__ int boff_s, total_s;
  const int t = threadIdx.x, l = t & 63, wid = t >> 6;
  if (t < 64){
    const int v = (t < SCAN_B) ? bsum[t] : 0;
    int x = v;
#pragma unroll
    for (int off=1; off<64; off<<=1){
      const int y = __shfl_up(x, off, 64);
      if (t >= off) x += y;
    }
    if (t == (int)blockIdx.x) boff_s = x - v;
    if (t == SCAN_B-1) total_s = x;
  }
  __syncthreads();
  const int i = blockIdx.x*1024 + t;
  const int v = (i < NN) ? deg[i] : 0;
  int x = v;
#pragma unroll
  for (int off=1; off<64; off<<=1){
    const int y = __shfl_up(x, off, 64);
    if (l >= off) x += y;
  }
  if (l == 63) ws[wid] = x;
  __syncthreads();
  if (t == 0){
    int run = 0;
#pragma unroll
    for (int k=0;k<16;++k){ const int tmp = ws[k]; ws[k] = run; run += tmp; }
  }
  __syncthreads();
  if (i < NN){
    const int excl = boff_s + ws[wid] + (x - v);
    rowptr[i] = excl; fillptr[i] = excl;
  }
  if (blockIdx.x == 0 && t == 0) rowptr[NN] = total_s;
}

// fill: one packed int2 {edge_id, src} scattered store per edge
__global__ void k_fill(const int* __restrict__ dst, const int* __restrict__ src,
                       int* __restrict__ fillptr, int2* __restrict__ esrc){
  for (int i = blockIdx.x*blockDim.x + threadIdx.x; i < NE; i += gridDim.x*blockDim.x){
    const int p = atomicAdd(&fillptr[dst[i]], 1);
    esrc[p] = make_int2(i, src[i]);
  }
}

// ---------- fused edge MLP -> ee: wave-independent, zero LDS/barriers ----------
__global__ __launch_bounds__(256, 4) void k_edge(
    const float* __restrict__ efeat, const float* __restrict__ rij,
    const short* __restrict__ we1b, const float* __restrict__ be1,
    const short* __restrict__ we2b, const float* __restrict__ w2pk,
    float* __restrict__ ee)
{
  const int tid = threadIdx.x;
  const int w = tid >> 6, l = tid & 63, l15 = l & 15, lq = l >> 4;
  const int e0w = blockIdx.x * 64 + w * 16;

  const float* erow = efeat + (size_t)(e0w + l15)*KIN + lq*8;
  const float4 r0 = *reinterpret_cast<const float4*>(erow);
  const float4 r1 = *reinterpret_cast<const float4*>(erow + 4);
  const float4 r2 = *reinterpret_cast<const float4*>(erow + 32);
  const float4 r3 = *reinterpret_cast<const float4*>(erow + 36);
  const float4 r4 = *reinterpret_cast<const float4*>(erow + 64);
  const float4 r5 = *reinterpret_cast<const float4*>(erow + 68);
  const float4 r6 = *reinterpret_cast<const float4*>(erow + 96);
  const float4 r7 = *reinterpret_cast<const float4*>(erow + 100);
  const float rv = rij[e0w + l15];

  f32x4 acc_t0 = (f32x4)0.0f, acc_t1 = (f32x4)0.0f;
  float4 raw[8] = {r0,r1,r2,r3,r4,r5,r6,r7};
#pragma unroll
  for (int ks=0; ks<4; ++ks){
    const int k0 = ks*32 + lq*8;
    bf16x8 bfr;
    bfr[0]=f2b(raw[2*ks].x); bfr[1]=f2b(raw[2*ks].y); bfr[2]=f2b(raw[2*ks].z); bfr[3]=f2b(raw[2*ks].w);
    bfr[4]=f2b(raw[2*ks+1].x); bfr[5]=f2b(raw[2*ks+1].y); bfr[6]=f2b(raw[2*ks+1].z); bfr[7]=f2b(raw[2*ks+1].w);
    const bf16x8 a0 = *reinterpret_cast<const bf16x8*>(we1b + (l15     )*KIN + k0);
    const bf16x8 a1 = *reinterpret_cast<const bf16x8*>(we1b + (16 + l15)*KIN + k0);
    acc_t0 = __builtin_amdgcn_mfma_f32_16x16x32_bf16(a0, bfr, acc_t0, 0,0,0);
    acc_t1 = __builtin_amdgcn_mfma_f32_16x16x32_bf16(a1, bfr, acc_t1, 0,0,0);
  }

  const f32x4 b1a = *reinterpret_cast<const f32x4*>(be1 + lq*4);
  const f32x4 b1b = *reinterpret_cast<const f32x4*>(be1 + 16 + lq*4);
  const unsigned t0lo = packbf(sspf(acc_t0[0]+b1a[0]), sspf(acc_t0[1]+b1a[1]));
  const unsigned t0hi = packbf(sspf(acc_t0[2]+b1a[2]), sspf(acc_t0[3]+b1a[3]));
  const unsigned t1lo = packbf(sspf(acc_t1[0]+b1b[0]), sspf(acc_t1[1]+b1b[1]));
  const unsigned t1hi = packbf(sspf(acc_t1[2]+b1b[2]), sspf(acc_t1[3]+b1b[3]));

  const int srcA = ((lq & 1) << 5) + l15;
  const int srcB = srcA + 16;
  const int a_lo0 = __shfl((int)t0lo, srcA, 64), a_hi0 = __shfl((int)t0hi, srcA, 64);
  const int b_lo0 = __shfl((int)t0lo, srcB, 64), b_hi0 = __shfl((int)t0hi, srcB, 64);
  const int a_lo1 = __shfl((int)t1lo, srcA, 64), a_hi1 = __shfl((int)t1hi, srcA, 64);
  const int b_lo1 = __shfl((int)t1lo, srcB, 64), b_hi1 = __shfl((int)t1hi, srcB, 64);
  const bool th1sel = (lq & 2);
  union { int u[4]; bf16x8 v; } bx;
  bx.u[0] = th1sel ? a_lo1 : a_lo0;
  bx.u[1] = th1sel ? a_hi1 : a_hi0;
  bx.u[2] = th1sel ? b_lo1 : b_lo0;
  bx.u[3] = th1sel ? b_hi1 : b_hi0;

  const float* pkb = w2pk + lq*8;
  float pe[8];
#pragma unroll
  for (int h=0;h<8;++h) pe[h] = 0.f;
#pragma unroll
  for (int cht=0; cht<16; ++cht){
    const bf16x8 a2 = *reinterpret_cast<const bf16x8*>(we2b + (cht*16 + l15)*32 + lq*8);
    const f32x4 d = __builtin_amdgcn_mfma_f32_16x16x32_bf16(a2, bx.v, (f32x4)0.0f, 0,0,0);
    const f32x4 b2v = *reinterpret_cast<const f32x4*>(pkb + cht*32);
    const f32x4 aev = *reinterpret_cast<const f32x4*>(pkb + cht*32 + 4);
    float s = 0.f;
#pragma unroll
    for (int j=0;j<4;++j) s = fmaf(sspf(d[j] + b2v[j]), aev[j], s);
    pe[cht>>1] += s;
  }
#pragma unroll
  for (int h=0;h<8;++h){
    pe[h] += __shfl_xor(pe[h], 16, 64);
    pe[h] += __shfl_xor(pe[h], 32, 64);
  }
  const float fcv = (rv < 5.0f) ? 0.5f*(__cosf(0.62831853071795864f*rv) + 1.0f) : 0.0f;
  const float o0 = (lq==0) ? pe[0] : (lq==1) ? pe[2] : (lq==2) ? pe[4] : pe[6];
  const float o1 = (lq==0) ? pe[1] : (lq==1) ? pe[3] : (lq==2) ? pe[5] : pe[7];
  float2 outv; outv.x = o0*fcv; outv.y = o1*fcv;
  *reinterpret_cast<float2*>(ee + (size_t)(e0w + l15)*8 + lq*2) = outv;
}

// ---------- fused softmax + aggregation: WAVE per node, zero LDS, zero barriers ----------
// Phase 1/2: per-head max & sum via (8 slots x 8 heads) gathers + shfl reduce.
// Agg: coef recomputed inline (m,s broadcast via shfl) -> no coef buffer, any degree.
__global__ __launch_bounds__(256) void k_sa(
    const int* __restrict__ rowptr, const int2* __restrict__ esrc,
    const float* __restrict__ el, const float* __restrict__ er,
    const float* __restrict__ ee, const short* __restrict__ featb,
    const float* __restrict__ bias, float* __restrict__ out)
{
  const int t = threadIdx.x, l = t & 63, w = t >> 6;
  const int n = blockIdx.x*4 + w;
  const int beg = rowptr[n], end = rowptr[n+1];
  const int h = l & 7, slot = l >> 3;
  const float erh = er[(size_t)n*8 + h];

  // pass 1: per-head max
  float m = -3e38f;
  for (int p = beg + slot; p < end; p += 8){
    const int2 es = esrc[p];
    float e = ee[(size_t)es.x*8 + h] + el[(size_t)es.y*8 + h] + erh;
    e = e > 0.f ? e : 0.2f*e;
    m = fmaxf(m, e);
  }
  m = fmaxf(m, __shfl_xor(m, 8, 64));
  m = fmaxf(m, __shfl_xor(m, 16, 64));
  m = fmaxf(m, __shfl_xor(m, 32, 64));

  // pass 2: per-head sum of exp
  float s = 0.f;
  for (int p = beg + slot; p < end; p += 8){
    const int2 es = esrc[p];
    float e = ee[(size_t)es.x*8 + h] + el[(size_t)es.y*8 + h] + erh;
    e = e > 0.f ? e : 0.2f*e;
    s += __expf(e - m);
  }
  s += __shfl_xor(s, 8, 64);
  s += __shfl_xor(s, 16, 64);
  s += __shfl_xor(s, 32, 64);

  // agg: 2 edge streams x 32 channel-lanes; coef fused
  const int stream = l >> 5, cl = l & 31, hh = cl >> 2;
  const float m_hh  = __shfl(m, hh, 64);
  const float s_hh  = __shfl(s, hh, 64);
  const float er_hh = __shfl(erh, hh, 64);
  const float is_hh = 1.0f / s_hh;
  float acc[8];
#pragma unroll
  for (int k=0;k<8;++k) acc[k] = 0.f;
  for (int p = beg + stream; p < end; p += 2){
    const int2 es = esrc[p];
    const float x = ee[(size_t)es.x*8 + hh];
    float e = x + el[(size_t)es.y*8 + hh] + er_hh;
    e = e > 0.f ? e : 0.2f*e;
    const float c = __expf(e - m_hh) * is_hh * x;
    const short8v fv = *reinterpret_cast<const short8v*>(featb + (size_t)es.y*HD + cl*8);
#pragma unroll
    for (int k=0;k<8;++k) acc[k] = fmaf(c, b2f(fv[k]), acc[k]);
  }
#pragma unroll
  for (int k=0;k<8;++k) acc[k] += __shfl_xor(acc[k], 32, 64);
  if (l < 32){
    const float4 b0 = *reinterpret_cast<const float4*>(bias + cl*8);
    const float4 b1 = *reinterpret_cast<const float4*>(bias + cl*8 + 4);
    float4 o0, o1;
    o0.x=acc[0]+b0.x; o0.y=acc[1]+b0.y; o0.z=acc[2]+b0.z; o0.w=acc[3]+b0.w;
    o1.x=acc[4]+b1.x; o1.y=acc[5]+b1.y; o1.z=acc[6]+b1.z; o1.w=acc[7]+b1.w;
    *reinterpret_cast<float4*>(out + (size_t)n*HD + cl*8) = o0;
    *reinterpret_cast<float4*>(out + (size_t)n*HD + cl*8 + 4) = o1;
  }
}

extern "C" void kernel_launch(void* const* d_in, const int* in_sizes, int n_in,
                              void* d_out, int out_size, void* d_ws, size_t ws_size,
                              hipStream_t stream) {
  const float* nfeat  = (const float*)d_in[0];
  const float* efeat  = (const float*)d_in[1];
  const float* rij    = (const float*)d_in[2];
  const int*   src    = (const int*)d_in[3];
  const int*   dst    = (const int*)d_in[4];
  const float* W_fc   = (const float*)d_in[5];
  const float* W_e1   = (const float*)d_in[6];
  const float* b_e1   = (const float*)d_in[7];
  const float* W_e2   = (const float*)d_in[8];
  const float* b_e2   = (const float*)d_in[9];
  const float* attn_l = (const float*)d_in[10];
  const float* attn_r = (const float*)d_in[11];
  const float* attn_e = (const float*)d_in[12];
  const float* bias   = (const float*)d_in[13];
  float* out = (float*)d_out;

  size_t off = 0;
  auto carve = [&](size_t nbytes) -> void* {
    void* p = (char*)d_ws + off;
    off += (nbytes + 255) & ~(size_t)255;
    return p;
  };
  short* featb = (short*)carve((size_t)NN*HD*2);
  float* el    = (float*)carve((size_t)NN*8*4);
  float* er    = (float*)carve((size_t)NN*8*4);
  float* ee    = (float*)carve((size_t)NE*8*4);
  int* deg     = (int*)carve((size_t)NN*4);
  int* rowptr  = (int*)carve((size_t)(NN+1)*4);
  int* fillptr = (int*)carve((size_t)(NN+1)*4);
  int2* esrc   = (int2*)carve((size_t)NE*8);
  int* bsum    = (int*)carve((size_t)SCAN_B*4);
  short* wfcb  = (short*)carve((size_t)HD*KIN*2);
  short* we1b  = (short*)carve((size_t)32*KIN*2);
  short* we2b  = (short*)carve((size_t)HD*32*2);
  float* w2pk  = (float*)carve((size_t)512*4);

  hipMemsetAsync(deg, 0, (size_t)NN*4, stream);
  k_cvh<<<1024, 256, 0, stream>>>(W_fc, W_e1, W_e2, b_e2, attn_e, dst,
                                  wfcb, we1b, we2b, w2pk, deg);
  k_feat<<<(NN+63)/64, 256, 0, stream>>>(nfeat, wfcb, attn_l, attn_r, featb, el, er);
  k_scanA<<<SCAN_B, 1024, 0, stream>>>(deg, bsum);
  k_scanC<<<SCAN_B, 1024, 0, stream>>>(deg, bsum, rowptr, fillptr);
  k_fill<<<1024, 256, 0, stream>>>(dst, src, fillptr, esrc);
  k_edge<<<NE/64, 256, 0, stream>>>(efeat, rij, we1b, b_e1, we2b, w2pk, ee);
  k_sa<<<(NN+3)/4, 256, 0, stream>>>(rowptr, esrc, el, er, ee, featb, bias, out);
}

// Round 10
// 415.426 us; speedup vs baseline: 1.5792x; 1.0625x over previous
//
#include <hip/hip_runtime.h>
#include <hip/hip_bf16.h>

#define NN 50000
#define NE 800000
#define HD 256
#define KIN 128
#define SCAN_B 49

typedef __attribute__((ext_vector_type(8))) short bf16x8;
typedef __attribute__((ext_vector_type(8))) short short8v;
typedef __attribute__((ext_vector_type(4))) float f32x4;

static __device__ __forceinline__ short f2b(float f){
  union { __hip_bfloat16 h; short s; } u;
  u.h = __float2bfloat16(f);
  return u.s;
}
static __device__ __forceinline__ float b2f(short s){
  union { __hip_bfloat16 h; short s; } u;
  u.s = s;
  return __bfloat162float(u.h);
}
static __device__ __forceinline__ unsigned packbf(float a, float b){
  union { short s[2]; unsigned u; } z;
  z.s[0] = f2b(a); z.s[1] = f2b(b);
  return z.u;
}
// softplus(x)-log(2) on raw v_exp/v_log
static __device__ __forceinline__ float sspf(float x){
#if __has_builtin(__builtin_amdgcn_exp2f) && __has_builtin(__builtin_amdgcn_logf)
  const float t = __builtin_amdgcn_exp2f(fabsf(x) * -1.4426950408889634f);
  return fmaf(__builtin_amdgcn_logf(1.0f + t) - 1.0f, 0.69314718055994531f, fmaxf(x, 0.0f));
#else
  const float t = __expf(-fabsf(x));
  return fmaxf(x, 0.0f) + __logf(1.0f + t) - 0.69314718055994531f;
#endif
}

// ---------- weight fp32 -> bf16 + packed epilogue table + degree histogram ----------
__global__ void k_cvh(const float* __restrict__ wfc, const float* __restrict__ we1,
                      const float* __restrict__ we2,
                      const float* __restrict__ be2, const float* __restrict__ attn_e,
                      const int* __restrict__ dst,
                      short* __restrict__ wfcb, short* __restrict__ we1b,
                      short* __restrict__ we2b, float* __restrict__ w2pk,
                      int* __restrict__ deg){
  const int i = blockIdx.x*256 + threadIdx.x;
  if (i < HD*KIN) wfcb[i] = f2b(wfc[i]);
  if (i < 32*KIN) we1b[i] = f2b(we1[i]);
  if (i < HD*32)  we2b[i] = f2b(we2[i]);
  if (i < 512){
    const int cht = i >> 5, r = i & 31, lq = r >> 3, j = r & 7;
    const int ch = cht*16 + lq*4 + (j & 3);
    w2pk[i] = (j < 4) ? be2[ch] : attn_e[ch];
  }
  for (int e = i; e < NE; e += gridDim.x*blockDim.x)
    atomicAdd(&deg[dst[e]], 1);
}

// ---------- feat = nfeat @ W_fc^T  (+ el, er) ----------
__global__ __launch_bounds__(256) void k_feat(
    const float* __restrict__ nfeat, const short* __restrict__ wfcb,
    const float* __restrict__ attn_l, const float* __restrict__ attn_r,
    short* __restrict__ featb, float* __restrict__ el, float* __restrict__ er)
{
  const int n0 = blockIdx.x * 64;
  const int tid = threadIdx.x;
  const int w = tid >> 6, l = tid & 63, l15 = l & 15, lq = l >> 4;

  f32x4 acc[4][4];
#pragma unroll
  for (int a=0;a<4;++a)
#pragma unroll
    for (int b=0;b<4;++b) acc[a][b] = (f32x4)0.0f;

#pragma unroll
  for (int ks=0; ks<4; ++ks){
    const int k0 = ks*32 + lq*8;
    bf16x8 af[4];
#pragma unroll
    for (int tr=0; tr<4; ++tr){
      int row = n0 + tr*16 + l15;
      if (row >= NN) row = NN-1;
      const float4 x0 = *reinterpret_cast<const float4*>(nfeat + (size_t)row*KIN + k0);
      const float4 x1 = *reinterpret_cast<const float4*>(nfeat + (size_t)row*KIN + k0 + 4);
      af[tr][0]=f2b(x0.x); af[tr][1]=f2b(x0.y); af[tr][2]=f2b(x0.z); af[tr][3]=f2b(x0.w);
      af[tr][4]=f2b(x1.x); af[tr][5]=f2b(x1.y); af[tr][6]=f2b(x1.z); af[tr][7]=f2b(x1.w);
    }
#pragma unroll
    for (int tc=0; tc<4; ++tc){
      const int c = w*64 + tc*16 + l15;
      const bf16x8 bfrag = *reinterpret_cast<const bf16x8*>(wfcb + c*KIN + k0);
#pragma unroll
      for (int tr=0; tr<4; ++tr)
        acc[tr][tc] = __builtin_amdgcn_mfma_f32_16x16x32_bf16(af[tr], bfrag, acc[tr][tc], 0,0,0);
    }
  }

  float alr[4], arr_[4];
#pragma unroll
  for (int tc=0;tc<4;++tc){
    const int c = w*64 + tc*16 + l15;
    alr[tc] = attn_l[c]; arr_[tc] = attn_r[c];
  }
  float pl[4][4][2], pr[4][4][2];
#pragma unroll
  for (int tr=0;tr<4;++tr)
#pragma unroll
    for (int j=0;j<4;++j){ pl[tr][j][0]=pl[tr][j][1]=0.f; pr[tr][j][0]=pr[tr][j][1]=0.f; }

#pragma unroll
  for (int tr=0;tr<4;++tr){
    const int rowb = tr*16 + lq*4;
#pragma unroll
    for (int tc=0;tc<4;++tc){
      const int c = w*64 + tc*16 + l15;
      const int h2 = tc>>1;
#pragma unroll
      for (int j=0;j<4;++j){
        const float v = acc[tr][tc][j];
        const int node = n0 + rowb + j;
        if (node < NN) featb[node*HD + c] = f2b(v);
        pl[tr][j][h2] += v*alr[tc];
        pr[tr][j][h2] += v*arr_[tc];
      }
    }
  }
#pragma unroll
  for (int m=1;m<16;m<<=1){
#pragma unroll
    for (int tr=0;tr<4;++tr)
#pragma unroll
      for (int j=0;j<4;++j){
        pl[tr][j][0] += __shfl_xor(pl[tr][j][0], m, 64);
        pl[tr][j][1] += __shfl_xor(pl[tr][j][1], m, 64);
        pr[tr][j][0] += __shfl_xor(pr[tr][j][0], m, 64);
        pr[tr][j][1] += __shfl_xor(pr[tr][j][1], m, 64);
      }
  }
#pragma unroll
  for (int tr=0;tr<4;++tr)
#pragma unroll
    for (int j=0;j<4;++j)
      if (l15 == tr*4+j){
        const int node = n0 + tr*16 + lq*4 + j;
        if (node < NN){
          el[node*8 + 2*w + 0] = pl[tr][j][0];
          el[node*8 + 2*w + 1] = pl[tr][j][1];
          er[node*8 + 2*w + 0] = pr[tr][j][0];
          er[node*8 + 2*w + 1] = pr[tr][j][1];
        }
      }
}

// ---------- CSR scan ----------
__global__ __launch_bounds__(1024) void k_scanA(const int* __restrict__ deg,
                                                int* __restrict__ bsum){
  __shared__ int ws[16];
  const int t = threadIdx.x;
  const int i = blockIdx.x*1024 + t;
  int v = (i < NN) ? deg[i] : 0;
#pragma unroll
  for (int m=1;m<64;m<<=1) v += __shfl_xor(v, m, 64);
  if ((t & 63) == 0) ws[t >> 6] = v;
  __syncthreads();
  if (t == 0){
    int s = 0;
#pragma unroll
    for (int k=0;k<16;++k) s += ws[k];
    bsum[blockIdx.x] = s;
  }
}

__global__ __launch_bounds__(1024) void k_scanC(const int* __restrict__ deg,
                                                const int* __restrict__ bsum,
                                                int* __restrict__ rowptr,
                                                int* __restrict__ fillptr){
  __shared__ int ws[16];
  __shared__ int boff_s, total_s;
  const int t = threadIdx.x, l = t & 63, wid = t >> 6;
  if (t < 64){
    const int v = (t < SCAN_B) ? bsum[t] : 0;
    int x = v;
#pragma unroll
    for (int off=1; off<64; off<<=1){
      const int y = __shfl_up(x, off, 64);
      if (t >= off) x += y;
    }
    if (t == (int)blockIdx.x) boff_s = x - v;
    if (t == SCAN_B-1) total_s = x;
  }
  __syncthreads();
  const int i = blockIdx.x*1024 + t;
  const int v = (i < NN) ? deg[i] : 0;
  int x = v;
#pragma unroll
  for (int off=1; off<64; off<<=1){
    const int y = __shfl_up(x, off, 64);
    if (l >= off) x += y;
  }
  if (l == 63) ws[wid] = x;
  __syncthreads();
  if (t == 0){
    int run = 0;
#pragma unroll
    for (int k=0;k<16;++k){ const int tmp = ws[k]; ws[k] = run; run += tmp; }
  }
  __syncthreads();
  if (i < NN){
    const int excl = boff_s + ws[wid] + (x - v);
    rowptr[i] = excl; fillptr[i] = excl;
  }
  if (blockIdx.x == 0 && t == 0) rowptr[NN] = total_s;
}

__global__ void k_fill(const int* __restrict__ dst, const int* __restrict__ src,
                       int* __restrict__ fillptr, int2* __restrict__ esrc){
  for (int i = blockIdx.x*blockDim.x + threadIdx.x; i < NE; i += gridDim.x*blockDim.x){
    const int p = atomicAdd(&fillptr[dst[i]], 1);
    esrc[p] = make_int2(i, src[i]);
  }
}

// ---------- fused edge MLP -> ee: wave-independent, zero LDS/barriers ----------
__global__ __launch_bounds__(256, 4) void k_edge(
    const float* __restrict__ efeat, const float* __restrict__ rij,
    const short* __restrict__ we1b, const float* __restrict__ be1,
    const short* __restrict__ we2b, const float* __restrict__ w2pk,
    float* __restrict__ ee)
{
  const int tid = threadIdx.x;
  const int w = tid >> 6, l = tid & 63, l15 = l & 15, lq = l >> 4;
  const int e0w = blockIdx.x * 64 + w * 16;

  const float* erow = efeat + (size_t)(e0w + l15)*KIN + lq*8;
  const float4 r0 = *reinterpret_cast<const float4*>(erow);
  const float4 r1 = *reinterpret_cast<const float4*>(erow + 4);
  const float4 r2 = *reinterpret_cast<const float4*>(erow + 32);
  const float4 r3 = *reinterpret_cast<const float4*>(erow + 36);
  const float4 r4 = *reinterpret_cast<const float4*>(erow + 64);
  const float4 r5 = *reinterpret_cast<const float4*>(erow + 68);
  const float4 r6 = *reinterpret_cast<const float4*>(erow + 96);
  const float4 r7 = *reinterpret_cast<const float4*>(erow + 100);
  const float rv = rij[e0w + l15];

  f32x4 acc_t0 = (f32x4)0.0f, acc_t1 = (f32x4)0.0f;
  float4 raw[8] = {r0,r1,r2,r3,r4,r5,r6,r7};
#pragma unroll
  for (int ks=0; ks<4; ++ks){
    const int k0 = ks*32 + lq*8;
    bf16x8 bfr;
    bfr[0]=f2b(raw[2*ks].x); bfr[1]=f2b(raw[2*ks].y); bfr[2]=f2b(raw[2*ks].z); bfr[3]=f2b(raw[2*ks].w);
    bfr[4]=f2b(raw[2*ks+1].x); bfr[5]=f2b(raw[2*ks+1].y); bfr[6]=f2b(raw[2*ks+1].z); bfr[7]=f2b(raw[2*ks+1].w);
    const bf16x8 a0 = *reinterpret_cast<const bf16x8*>(we1b + (l15     )*KIN + k0);
    const bf16x8 a1 = *reinterpret_cast<const bf16x8*>(we1b + (16 + l15)*KIN + k0);
    acc_t0 = __builtin_amdgcn_mfma_f32_16x16x32_bf16(a0, bfr, acc_t0, 0,0,0);
    acc_t1 = __builtin_amdgcn_mfma_f32_16x16x32_bf16(a1, bfr, acc_t1, 0,0,0);
  }

  const f32x4 b1a = *reinterpret_cast<const f32x4*>(be1 + lq*4);
  const f32x4 b1b = *reinterpret_cast<const f32x4*>(be1 + 16 + lq*4);
  const unsigned t0lo = packbf(sspf(acc_t0[0]+b1a[0]), sspf(acc_t0[1]+b1a[1]));
  const unsigned t0hi = packbf(sspf(acc_t0[2]+b1a[2]), sspf(acc_t0[3]+b1a[3]));
  const unsigned t1lo = packbf(sspf(acc_t1[0]+b1b[0]), sspf(acc_t1[1]+b1b[1]));
  const unsigned t1hi = packbf(sspf(acc_t1[2]+b1b[2]), sspf(acc_t1[3]+b1b[3]));

  const int srcA = ((lq & 1) << 5) + l15;
  const int srcB = srcA + 16;
  const int a_lo0 = __shfl((int)t0lo, srcA, 64), a_hi0 = __shfl((int)t0hi, srcA, 64);
  const int b_lo0 = __shfl((int)t0lo, srcB, 64), b_hi0 = __shfl((int)t0hi, srcB, 64);
  const int a_lo1 = __shfl((int)t1lo, srcA, 64), a_hi1 = __shfl((int)t1hi, srcA, 64);
  const int b_lo1 = __shfl((int)t1lo, srcB, 64), b_hi1 = __shfl((int)t1hi, srcB, 64);
  const bool th1sel = (lq & 2);
  union { int u[4]; bf16x8 v; } bx;
  bx.u[0] = th1sel ? a_lo1 : a_lo0;
  bx.u[1] = th1sel ? a_hi1 : a_hi0;
  bx.u[2] = th1sel ? b_lo1 : b_lo0;
  bx.u[3] = th1sel ? b_hi1 : b_hi0;

  const float* pkb = w2pk + lq*8;
  float pe[8];
#pragma unroll
  for (int h=0;h<8;++h) pe[h] = 0.f;
#pragma unroll
  for (int cht=0; cht<16; ++cht){
    const bf16x8 a2 = *reinterpret_cast<const bf16x8*>(we2b + (cht*16 + l15)*32 + lq*8);
    const f32x4 d = __builtin_amdgcn_mfma_f32_16x16x32_bf16(a2, bx.v, (f32x4)0.0f, 0,0,0);
    const f32x4 b2v = *reinterpret_cast<const f32x4*>(pkb + cht*32);
    const f32x4 aev = *reinterpret_cast<const f32x4*>(pkb + cht*32 + 4);
    float s = 0.f;
#pragma unroll
    for (int j=0;j<4;++j) s = fmaf(sspf(d[j] + b2v[j]), aev[j], s);
    pe[cht>>1] += s;
  }
#pragma unroll
  for (int h=0;h<8;++h){
    pe[h] += __shfl_xor(pe[h], 16, 64);
    pe[h] += __shfl_xor(pe[h], 32, 64);
  }
  const float fcv = (rv < 5.0f) ? 0.5f*(__cosf(0.62831853071795864f*rv) + 1.0f) : 0.0f;
  const float o0 = (lq==0) ? pe[0] : (lq==1) ? pe[2] : (lq==2) ? pe[4] : pe[6];
  const float o1 = (lq==0) ? pe[1] : (lq==1) ? pe[3] : (lq==2) ? pe[5] : pe[7];
  float2 outv; outv.x = o0*fcv; outv.y = o1*fcv;
  *reinterpret_cast<float2*>(ee + (size_t)(e0w + l15)*8 + lq*2) = outv;
}

// ---------- SINGLE-PASS softmax+aggregation: wave per node ----------
// No max pass (|e| <~ 10 << 88, exp cannot overflow); normalization deferred:
// out[n,h,:] = (sum_e exp(e)*ee*feat[src]) / (sum_e exp(e)) + bias.
__global__ __launch_bounds__(256) void k_sa(
    const int* __restrict__ rowptr, const int2* __restrict__ esrc,
    const float* __restrict__ el, const float* __restrict__ er,
    const float* __restrict__ ee, const short* __restrict__ featb,
    const float* __restrict__ bias, float* __restrict__ out)
{
  const int t = threadIdx.x, l = t & 63, w = t >> 6;
  const int n = blockIdx.x*4 + w;
  const int beg = rowptr[n], end = rowptr[n+1];
  const int stream = l >> 5, cl = l & 31, hh = cl >> 2;
  const float er_hh = er[(size_t)n*8 + hh];

  float acc[8];
#pragma unroll
  for (int k=0;k<8;++k) acc[k] = 0.f;
  float s = 0.f;
  for (int p = beg + stream; p < end; p += 2){
    const int2 es = esrc[p];
    const float x = ee[(size_t)es.x*8 + hh];
    float e = x + el[(size_t)es.y*8 + hh] + er_hh;
    e = e > 0.f ? e : 0.2f*e;
    const float pex = __expf(e);
    const float c = pex * x;
    s += pex;
    const short8v fv = *reinterpret_cast<const short8v*>(featb + (size_t)es.y*HD + cl*8);
#pragma unroll
    for (int k=0;k<8;++k) acc[k] = fmaf(c, b2f(fv[k]), acc[k]);
  }
  // merge the two edge streams (lane l <-> l+32 hold same channels)
  s += __shfl_xor(s, 32, 64);
#pragma unroll
  for (int k=0;k<8;++k) acc[k] += __shfl_xor(acc[k], 32, 64);
  if (l < 32){
    const float inv = (s > 0.f) ? 1.0f / s : 0.0f;
    const float4 b0 = *reinterpret_cast<const float4*>(bias + cl*8);
    const float4 b1 = *reinterpret_cast<const float4*>(bias + cl*8 + 4);
    float4 o0, o1;
    o0.x=fmaf(acc[0],inv,b0.x); o0.y=fmaf(acc[1],inv,b0.y);
    o0.z=fmaf(acc[2],inv,b0.z); o0.w=fmaf(acc[3],inv,b0.w);
    o1.x=fmaf(acc[4],inv,b1.x); o1.y=fmaf(acc[5],inv,b1.y);
    o1.z=fmaf(acc[6],inv,b1.z); o1.w=fmaf(acc[7],inv,b1.w);
    *reinterpret_cast<float4*>(out + (size_t)n*HD + cl*8) = o0;
    *reinterpret_cast<float4*>(out + (size_t)n*HD + cl*8 + 4) = o1;
  }
}

extern "C" void kernel_launch(void* const* d_in, const int* in_sizes, int n_in,
                              void* d_out, int out_size, void* d_ws, size_t ws_size,
                              hipStream_t stream) {
  const float* nfeat  = (const float*)d_in[0];
  const float* efeat  = (const float*)d_in[1];
  const float* rij    = (const float*)d_in[2];
  const int*   src    = (const int*)d_in[3];
  const int*   dst    = (const int*)d_in[4];
  const float* W_fc   = (const float*)d_in[5];
  const float* W_e1   = (const float*)d_in[6];
  const float* b_e1   = (const float*)d_in[7];
  const float* W_e2   = (const float*)d_in[8];
  const float* b_e2   = (const float*)d_in[9];
  const float* attn_l = (const float*)d_in[10];
  const float* attn_r = (const float*)d_in[11];
  const float* attn_e = (const float*)d_in[12];
  const float* bias   = (const float*)d_in[13];
  float* out = (float*)d_out;

  size_t off = 0;
  auto carve = [&](size_t nbytes) -> void* {
    void* p = (char*)d_ws + off;
    off += (nbytes + 255) & ~(size_t)255;
    return p;
  };
  short* featb = (short*)carve((size_t)NN*HD*2);
  float* el    = (float*)carve((size_t)NN*8*4);
  float* er    = (float*)carve((size_t)NN*8*4);
  float* ee    = (float*)carve((size_t)NE*8*4);
  int* deg     = (int*)carve((size_t)NN*4);
  int* rowptr  = (int*)carve((size_t)(NN+1)*4);
  int* fillptr = (int*)carve((size_t)(NN+1)*4);
  int2* esrc   = (int2*)carve((size_t)NE*8);
  int* bsum    = (int*)carve((size_t)SCAN_B*4);
  short* wfcb  = (short*)carve((size_t)HD*KIN*2);
  short* we1b  = (short*)carve((size_t)32*KIN*2);
  short* we2b  = (short*)carve((size_t)HD*32*2);
  float* w2pk  = (float*)carve((size_t)512*4);

  hipMemsetAsync(deg, 0, (size_t)NN*4, stream);
  k_cvh<<<1024, 256, 0, stream>>>(W_fc, W_e1, W_e2, b_e2, attn_e, dst,
                                  wfcb, we1b, we2b, w2pk, deg);
  k_feat<<<(NN+63)/64, 256, 0, stream>>>(nfeat, wfcb, attn_l, attn_r, featb, el, er);
  k_scanA<<<SCAN_B, 1024, 0, stream>>>(deg, bsum);
  k_scanC<<<SCAN_B, 1024, 0, stream>>>(deg, bsum, rowptr, fillptr);
  k_fill<<<1024, 256, 0, stream>>>(dst, src, fillptr, esrc);
  k_edge<<<NE/64, 256, 0, stream>>>(efeat, rij, we1b, b_e1, we2b, w2pk, ee);
  k_sa<<<(NN+3)/4, 256, 0, stream>>>(rowptr, esrc, el, er, ee, featb, bias, out);
}

// Round 11
// 376.436 us; speedup vs baseline: 1.7427x; 1.1036x over previous
//
#include <hip/hip_runtime.h>
#include <hip/hip_bf16.h>

#define NN 50000
#define NE 800000
#define HD 256
#define KIN 128
#define SCAN_B 49

#define FB_FEAT 1563   // (NN+31)/32
#define FB_FILL 1024
#define FB_EDGE 12500  // NE/64

typedef __attribute__((ext_vector_type(8))) short bf16x8;
typedef __attribute__((ext_vector_type(8))) short short8v;
typedef __attribute__((ext_vector_type(4))) float f32x4;

static __device__ __forceinline__ short f2b(float f){
  union { __hip_bfloat16 h; short s; } u;
  u.h = __float2bfloat16(f);
  return u.s;
}
static __device__ __forceinline__ float b2f(short s){
  union { __hip_bfloat16 h; short s; } u;
  u.s = s;
  return __bfloat162float(u.h);
}
static __device__ __forceinline__ unsigned packbf(float a, float b){
  union { short s[2]; unsigned u; } z;
  z.s[0] = f2b(a); z.s[1] = f2b(b);
  return z.u;
}
// softplus(x)-log(2) on raw v_exp/v_log
static __device__ __forceinline__ float sspf(float x){
#if __has_builtin(__builtin_amdgcn_exp2f) && __has_builtin(__builtin_amdgcn_logf)
  const float t = __builtin_amdgcn_exp2f(fabsf(x) * -1.4426950408889634f);
  return fmaf(__builtin_amdgcn_logf(1.0f + t) - 1.0f, 0.69314718055994531f, fmaxf(x, 0.0f));
#else
  const float t = __expf(-fabsf(x));
  return fmaxf(x, 0.0f) + __logf(1.0f + t) - 0.69314718055994531f;
#endif
}

// ---------- weight fp32 -> bf16 + packed epilogue table + degree histogram ----------
__global__ void k_cvh(const float* __restrict__ wfc, const float* __restrict__ we1,
                      const float* __restrict__ we2,
                      const float* __restrict__ be2, const float* __restrict__ attn_e,
                      const int* __restrict__ dst,
                      short* __restrict__ wfcb, short* __restrict__ we1b,
                      short* __restrict__ we2b, float* __restrict__ w2pk,
                      int* __restrict__ deg){
  const int i = blockIdx.x*256 + threadIdx.x;
  if (i < HD*KIN) wfcb[i] = f2b(wfc[i]);
  if (i < 32*KIN) we1b[i] = f2b(we1[i]);
  if (i < HD*32)  we2b[i] = f2b(we2[i]);
  if (i < 512){
    const int cht = i >> 5, r = i & 31, lq = r >> 3, j = r & 7;
    const int ch = cht*16 + lq*4 + (j & 3);
    w2pk[i] = (j < 4) ? be2[ch] : attn_e[ch];
  }
  for (int e = i; e < NE; e += gridDim.x*blockDim.x)
    atomicAdd(&deg[dst[e]], 1);
}

// ---------- CSR scan ----------
__global__ __launch_bounds__(1024) void k_scanA(const int* __restrict__ deg,
                                                int* __restrict__ bsum){
  __shared__ int ws[16];
  const int t = threadIdx.x;
  const int i = blockIdx.x*1024 + t;
  int v = (i < NN) ? deg[i] : 0;
#pragma unroll
  for (int m=1;m<64;m<<=1) v += __shfl_xor(v, m, 64);
  if ((t & 63) == 0) ws[t >> 6] = v;
  __syncthreads();
  if (t == 0){
    int s = 0;
#pragma unroll
    for (int k=0;k<16;++k) s += ws[k];
    bsum[blockIdx.x] = s;
  }
}

__global__ __launch_bounds__(1024) void k_scanC(const int* __restrict__ deg,
                                                const int* __restrict__ bsum,
                                                int* __restrict__ rowptr,
                                                int* __restrict__ fillptr){
  __shared__ int ws[16];
  __shared__ int boff_s, total_s;
  const int t = threadIdx.x, l = t & 63, wid = t >> 6;
  if (t < 64){
    const int v = (t < SCAN_B) ? bsum[t] : 0;
    int x = v;
#pragma unroll
    for (int off=1; off<64; off<<=1){
      const int y = __shfl_up(x, off, 64);
      if (t >= off) x += y;
    }
    if (t == (int)blockIdx.x) boff_s = x - v;
    if (t == SCAN_B-1) total_s = x;
  }
  __syncthreads();
  const int i = blockIdx.x*1024 + t;
  const int v = (i < NN) ? deg[i] : 0;
  int x = v;
#pragma unroll
  for (int off=1; off<64; off<<=1){
    const int y = __shfl_up(x, off, 64);
    if (l >= off) x += y;
  }
  if (l == 63) ws[wid] = x;
  __syncthreads();
  if (t == 0){
    int run = 0;
#pragma unroll
    for (int k=0;k<16;++k){ const int tmp = ws[k]; ws[k] = run; run += tmp; }
  }
  __syncthreads();
  if (i < NN){
    const int excl = boff_s + ws[wid] + (x - v);
    rowptr[i] = excl; fillptr[i] = excl;
  }
  if (blockIdx.x == 0 && t == 0) rowptr[NN] = total_s;
}

// ---------- feat branch: 32-node tile (register diet for the fat kernel) ----------
static __device__ __forceinline__ void feat_body(
    int bid, int tid,
    const float* __restrict__ nfeat, const short* __restrict__ wfcb,
    const float* __restrict__ attn_l, const float* __restrict__ attn_r,
    short* __restrict__ featb, float* __restrict__ el, float* __restrict__ er)
{
  const int n0 = bid * 32;
  const int w = tid >> 6, l = tid & 63, l15 = l & 15, lq = l >> 4;

  f32x4 acc[2][4];
#pragma unroll
  for (int a=0;a<2;++a)
#pragma unroll
    for (int b=0;b<4;++b) acc[a][b] = (f32x4)0.0f;

#pragma unroll
  for (int ks=0; ks<4; ++ks){
    const int k0 = ks*32 + lq*8;
    bf16x8 af[2];
#pragma unroll
    for (int tr=0; tr<2; ++tr){
      int row = n0 + tr*16 + l15;
      if (row >= NN) row = NN-1;
      const float4 x0 = *reinterpret_cast<const float4*>(nfeat + (size_t)row*KIN + k0);
      const float4 x1 = *reinterpret_cast<const float4*>(nfeat + (size_t)row*KIN + k0 + 4);
      af[tr][0]=f2b(x0.x); af[tr][1]=f2b(x0.y); af[tr][2]=f2b(x0.z); af[tr][3]=f2b(x0.w);
      af[tr][4]=f2b(x1.x); af[tr][5]=f2b(x1.y); af[tr][6]=f2b(x1.z); af[tr][7]=f2b(x1.w);
    }
#pragma unroll
    for (int tc=0; tc<4; ++tc){
      const int c = w*64 + tc*16 + l15;
      const bf16x8 bfrag = *reinterpret_cast<const bf16x8*>(wfcb + c*KIN + k0);
#pragma unroll
      for (int tr=0; tr<2; ++tr)
        acc[tr][tc] = __builtin_amdgcn_mfma_f32_16x16x32_bf16(af[tr], bfrag, acc[tr][tc], 0,0,0);
    }
  }

  float alr[4], arr_[4];
#pragma unroll
  for (int tc=0;tc<4;++tc){
    const int c = w*64 + tc*16 + l15;
    alr[tc] = attn_l[c]; arr_[tc] = attn_r[c];
  }
  float pl[2][4][2], pr[2][4][2];
#pragma unroll
  for (int tr=0;tr<2;++tr)
#pragma unroll
    for (int j=0;j<4;++j){ pl[tr][j][0]=pl[tr][j][1]=0.f; pr[tr][j][0]=pr[tr][j][1]=0.f; }

#pragma unroll
  for (int tr=0;tr<2;++tr){
    const int rowb = tr*16 + lq*4;
#pragma unroll
    for (int tc=0;tc<4;++tc){
      const int c = w*64 + tc*16 + l15;
      const int h2 = tc>>1;
#pragma unroll
      for (int j=0;j<4;++j){
        const float v = acc[tr][tc][j];
        const int node = n0 + rowb + j;
        if (node < NN) featb[node*HD + c] = f2b(v);
        pl[tr][j][h2] += v*alr[tc];
        pr[tr][j][h2] += v*arr_[tc];
      }
    }
  }
#pragma unroll
  for (int m=1;m<16;m<<=1){
#pragma unroll
    for (int tr=0;tr<2;++tr)
#pragma unroll
      for (int j=0;j<4;++j){
        pl[tr][j][0] += __shfl_xor(pl[tr][j][0], m, 64);
        pl[tr][j][1] += __shfl_xor(pl[tr][j][1], m, 64);
        pr[tr][j][0] += __shfl_xor(pr[tr][j][0], m, 64);
        pr[tr][j][1] += __shfl_xor(pr[tr][j][1], m, 64);
      }
  }
#pragma unroll
  for (int tr=0;tr<2;++tr)
#pragma unroll
    for (int j=0;j<4;++j)
      if (l15 == tr*4+j){
        const int node = n0 + tr*16 + lq*4 + j;
        if (node < NN){
          el[node*8 + 2*w + 0] = pl[tr][j][0];
          el[node*8 + 2*w + 1] = pl[tr][j][1];
          er[node*8 + 2*w + 0] = pr[tr][j][0];
          er[node*8 + 2*w + 1] = pr[tr][j][1];
        }
      }
}

// ---------- fill branch ----------
static __device__ __forceinline__ void fill_body(
    int bid, int tid,
    const int* __restrict__ dst, const int* __restrict__ src,
    int* __restrict__ fillptr, int2* __restrict__ esrc)
{
  for (int i = bid*256 + tid; i < NE; i += FB_FILL*256){
    const int p = atomicAdd(&fillptr[dst[i]], 1);
    esrc[p] = make_int2(i, src[i]);
  }
}

// ---------- edge branch: wave-independent, zero LDS/barriers ----------
static __device__ __forceinline__ void edge_body(
    int bid, int tid,
    const float* __restrict__ efeat, const float* __restrict__ rij,
    const short* __restrict__ we1b, const float* __restrict__ be1,
    const short* __restrict__ we2b, const float* __restrict__ w2pk,
    float* __restrict__ ee)
{
  const int w = tid >> 6, l = tid & 63, l15 = l & 15, lq = l >> 4;
  const int e0w = bid * 64 + w * 16;

  const float* erow = efeat + (size_t)(e0w + l15)*KIN + lq*8;
  const float4 r0 = *reinterpret_cast<const float4*>(erow);
  const float4 r1 = *reinterpret_cast<const float4*>(erow + 4);
  const float4 r2 = *reinterpret_cast<const float4*>(erow + 32);
  const float4 r3 = *reinterpret_cast<const float4*>(erow + 36);
  const float4 r4 = *reinterpret_cast<const float4*>(erow + 64);
  const float4 r5 = *reinterpret_cast<const float4*>(erow + 68);
  const float4 r6 = *reinterpret_cast<const float4*>(erow + 96);
  const float4 r7 = *reinterpret_cast<const float4*>(erow + 100);
  const float rv = rij[e0w + l15];

  f32x4 acc_t0 = (f32x4)0.0f, acc_t1 = (f32x4)0.0f;
  float4 raw[8] = {r0,r1,r2,r3,r4,r5,r6,r7};
#pragma unroll
  for (int ks=0; ks<4; ++ks){
    const int k0 = ks*32 + lq*8;
    bf16x8 bfr;
    bfr[0]=f2b(raw[2*ks].x); bfr[1]=f2b(raw[2*ks].y); bfr[2]=f2b(raw[2*ks].z); bfr[3]=f2b(raw[2*ks].w);
    bfr[4]=f2b(raw[2*ks+1].x); bfr[5]=f2b(raw[2*ks+1].y); bfr[6]=f2b(raw[2*ks+1].z); bfr[7]=f2b(raw[2*ks+1].w);
    const bf16x8 a0 = *reinterpret_cast<const bf16x8*>(we1b + (l15     )*KIN + k0);
    const bf16x8 a1 = *reinterpret_cast<const bf16x8*>(we1b + (16 + l15)*KIN + k0);
    acc_t0 = __builtin_amdgcn_mfma_f32_16x16x32_bf16(a0, bfr, acc_t0, 0,0,0);
    acc_t1 = __builtin_amdgcn_mfma_f32_16x16x32_bf16(a1, bfr, acc_t1, 0,0,0);
  }

  const f32x4 b1a = *reinterpret_cast<const f32x4*>(be1 + lq*4);
  const f32x4 b1b = *reinterpret_cast<const f32x4*>(be1 + 16 + lq*4);
  const unsigned t0lo = packbf(sspf(acc_t0[0]+b1a[0]), sspf(acc_t0[1]+b1a[1]));
  const unsigned t0hi = packbf(sspf(acc_t0[2]+b1a[2]), sspf(acc_t0[3]+b1a[3]));
  const unsigned t1lo = packbf(sspf(acc_t1[0]+b1b[0]), sspf(acc_t1[1]+b1b[1]));
  const unsigned t1hi = packbf(sspf(acc_t1[2]+b1b[2]), sspf(acc_t1[3]+b1b[3]));

  const int srcA = ((lq & 1) << 5) + l15;
  const int srcB = srcA + 16;
  const int a_lo0 = __shfl((int)t0lo, srcA, 64), a_hi0 = __shfl((int)t0hi, srcA, 64);
  const int b_lo0 = __shfl((int)t0lo, srcB, 64), b_hi0 = __shfl((int)t0hi, srcB, 64);
  const int a_lo1 = __shfl((int)t1lo, srcA, 64), a_hi1 = __shfl((int)t1hi, srcA, 64);
  const int b_lo1 = __shfl((int)t1lo, srcB, 64), b_hi1 = __shfl((int)t1hi, srcB, 64);
  const bool th1sel = (lq & 2);
  union { int u[4]; bf16x8 v; } bx;
  bx.u[0] = th1sel ? a_lo1 : a_lo0;
  bx.u[1] = th1sel ? a_hi1 : a_hi0;
  bx.u[2] = th1sel ? b_lo1 : b_lo0;
  bx.u[3] = th1sel ? b_hi1 : b_hi0;

  const float* pkb = w2pk + lq*8;
  float pe[8];
#pragma unroll
  for (int h=0;h<8;++h) pe[h] = 0.f;
#pragma unroll
  for (int cht=0; cht<16; ++cht){
    const bf16x8 a2 = *reinterpret_cast<const bf16x8*>(we2b + (cht*16 + l15)*32 + lq*8);
    const f32x4 d = __builtin_amdgcn_mfma_f32_16x16x32_bf16(a2, bx.v, (f32x4)0.0f, 0,0,0);
    const f32x4 b2v = *reinterpret_cast<const f32x4*>(pkb + cht*32);
    const f32x4 aev = *reinterpret_cast<const f32x4*>(pkb + cht*32 + 4);
    float s = 0.f;
#pragma unroll
    for (int j=0;j<4;++j) s = fmaf(sspf(d[j] + b2v[j]), aev[j], s);
    pe[cht>>1] += s;
  }
#pragma unroll
  for (int h=0;h<8;++h){
    pe[h] += __shfl_xor(pe[h], 16, 64);
    pe[h] += __shfl_xor(pe[h], 32, 64);
  }
  const float fcv = (rv < 5.0f) ? 0.5f*(__cosf(0.62831853071795864f*rv) + 1.0f) : 0.0f;
  const float o0 = (lq==0) ? pe[0] : (lq==1) ? pe[2] : (lq==2) ? pe[4] : pe[6];
  const float o1 = (lq==0) ? pe[1] : (lq==1) ? pe[3] : (lq==2) ? pe[5] : pe[7];
  float2 outv; outv.x = o0*fcv; outv.y = o1*fcv;
  *reinterpret_cast<float2*>(ee + (size_t)(e0w + l15)*8 + lq*2) = outv;
}

// ---------- FAT kernel: feat (0..1562) | fill (1563..2586) | edge (2587..15086) ----------
__global__ __launch_bounds__(256, 4) void k_big(
    const float* __restrict__ nfeat, const short* __restrict__ wfcb,
    const float* __restrict__ attn_l, const float* __restrict__ attn_r,
    short* __restrict__ featb, float* __restrict__ el, float* __restrict__ er,
    const int* __restrict__ dst, const int* __restrict__ src,
    int* __restrict__ fillptr, int2* __restrict__ esrc,
    const float* __restrict__ efeat, const float* __restrict__ rij,
    const short* __restrict__ we1b, const float* __restrict__ be1,
    const short* __restrict__ we2b, const float* __restrict__ w2pk,
    float* __restrict__ ee)
{
  const int bid = blockIdx.x, tid = threadIdx.x;
  if (bid < FB_FEAT){
    feat_body(bid, tid, nfeat, wfcb, attn_l, attn_r, featb, el, er);
  } else if (bid < FB_FEAT + FB_FILL){
    fill_body(bid - FB_FEAT, tid, dst, src, fillptr, esrc);
  } else {
    edge_body(bid - FB_FEAT - FB_FILL, tid, efeat, rij, we1b, be1, we2b, w2pk, ee);
  }
}

// ---------- SINGLE-PASS softmax+aggregation: wave per node ----------
__global__ __launch_bounds__(256) void k_sa(
    const int* __restrict__ rowptr, const int2* __restrict__ esrc,
    const float* __restrict__ el, const float* __restrict__ er,
    const float* __restrict__ ee, const short* __restrict__ featb,
    const float* __restrict__ bias, float* __restrict__ out)
{
  const int t = threadIdx.x, l = t & 63, w = t >> 6;
  const int n = blockIdx.x*4 + w;
  const int beg = rowptr[n], end = rowptr[n+1];
  const int stream = l >> 5, cl = l & 31, hh = cl >> 2;
  const float er_hh = er[(size_t)n*8 + hh];

  float acc[8];
#pragma unroll
  for (int k=0;k<8;++k) acc[k] = 0.f;
  float s = 0.f;
  for (int p = beg + stream; p < end; p += 2){
    const int2 es = esrc[p];
    const float x = ee[(size_t)es.x*8 + hh];
    float e = x + el[(size_t)es.y*8 + hh] + er_hh;
    e = e > 0.f ? e : 0.2f*e;
    const float pex = __expf(e);
    const float c = pex * x;
    s += pex;
    const short8v fv = *reinterpret_cast<const short8v*>(featb + (size_t)es.y*HD + cl*8);
#pragma unroll
    for (int k=0;k<8;++k) acc[k] = fmaf(c, b2f(fv[k]), acc[k]);
  }
  s += __shfl_xor(s, 32, 64);
#pragma unroll
  for (int k=0;k<8;++k) acc[k] += __shfl_xor(acc[k], 32, 64);
  if (l < 32){
    const float inv = (s > 0.f) ? 1.0f / s : 0.0f;
    const float4 b0 = *reinterpret_cast<const float4*>(bias + cl*8);
    const float4 b1 = *reinterpret_cast<const float4*>(bias + cl*8 + 4);
    float4 o0, o1;
    o0.x=fmaf(acc[0],inv,b0.x); o0.y=fmaf(acc[1],inv,b0.y);
    o0.z=fmaf(acc[2],inv,b0.z); o0.w=fmaf(acc[3],inv,b0.w);
    o1.x=fmaf(acc[4],inv,b1.x); o1.y=fmaf(acc[5],inv,b1.y);
    o1.z=fmaf(acc[6],inv,b1.z); o1.w=fmaf(acc[7],inv,b1.w);
    *reinterpret_cast<float4*>(out + (size_t)n*HD + cl*8) = o0;
    *reinterpret_cast<float4*>(out + (size_t)n*HD + cl*8 + 4) = o1;
  }
}

extern "C" void kernel_launch(void* const* d_in, const int* in_sizes, int n_in,
                              void* d_out, int out_size, void* d_ws, size_t ws_size,
                              hipStream_t stream) {
  const float* nfeat  = (const float*)d_in[0];
  const float* efeat  = (const float*)d_in[1];
  const float* rij    = (const float*)d_in[2];
  const int*   src    = (const int*)d_in[3];
  const int*   dst    = (const int*)d_in[4];
  const float* W_fc   = (const float*)d_in[5];
  const float* W_e1   = (const float*)d_in[6];
  const float* b_e1   = (const float*)d_in[7];
  const float* W_e2   = (const float*)d_in[8];
  const float* b_e2   = (const float*)d_in[9];
  const float* attn_l = (const float*)d_in[10];
  const float* attn_r = (const float*)d_in[11];
  const float* attn_e = (const float*)d_in[12];
  const float* bias   = (const float*)d_in[13];
  float* out = (float*)d_out;

  size_t off = 0;
  auto carve = [&](size_t nbytes) -> void* {
    void* p = (char*)d_ws + off;
    off += (nbytes + 255) & ~(size_t)255;
    return p;
  };
  short* featb = (short*)carve((size_t)NN*HD*2);
  float* el    = (float*)carve((size_t)NN*8*4);
  float* er    = (float*)carve((size_t)NN*8*4);
  float* ee    = (float*)carve((size_t)NE*8*4);
  int* deg     = (int*)carve((size_t)NN*4);
  int* rowptr  = (int*)carve((size_t)(NN+1)*4);
  int* fillptr = (int*)carve((size_t)(NN+1)*4);
  int2* esrc   = (int2*)carve((size_t)NE*8);
  int* bsum    = (int*)carve((size_t)SCAN_B*4);
  short* wfcb  = (short*)carve((size_t)HD*KIN*2);
  short* we1b  = (short*)carve((size_t)32*KIN*2);
  short* we2b  = (short*)carve((size_t)HD*32*2);
  float* w2pk  = (float*)carve((size_t)512*4);

  hipMemsetAsync(deg, 0, (size_t)NN*4, stream);
  k_cvh<<<1024, 256, 0, stream>>>(W_fc, W_e1, W_e2, b_e2, attn_e, dst,
                                  wfcb, we1b, we2b, w2pk, deg);
  k_scanA<<<SCAN_B, 1024, 0, stream>>>(deg, bsum);
  k_scanC<<<SCAN_B, 1024, 0, stream>>>(deg, bsum, rowptr, fillptr);
  k_big<<<FB_FEAT + FB_FILL + FB_EDGE, 256, 0, stream>>>(
      nfeat, wfcb, attn_l, attn_r, featb, el, er,
      dst, src, fillptr, esrc,
      efeat, rij, we1b, b_e1, we2b, w2pk, ee);
  k_sa<<<(NN+3)/4, 256, 0, stream>>>(rowptr, esrc, el, er, ee, featb, bias, out);
}